// Round 3
// baseline (255.216 us; speedup 1.0000x reference)
//
#include <hip/hip_runtime.h>
#include <hip/hip_bf16.h>
#include <string.h>

typedef __hip_bfloat16 bf16;
typedef __bf16 bf16x8 __attribute__((ext_vector_type(8)));
typedef float f32x4 __attribute__((ext_vector_type(4)));

typedef __attribute__((address_space(1))) void* gas_ptr;
typedef __attribute__((address_space(3))) void* las_ptr;

__device__ __forceinline__ void gload_lds16(const void* g, void* l) {
  __builtin_amdgcn_global_load_lds((gas_ptr)(void*)g, (las_ptr)l, 16, 0, 0);
}

// Inputs confirmed fp32 (rounds 2-8 passed with fp32 path).
// T2 swizzle convention for [row][32ch] bf16 tiles (64B rows): 16B-chunk index
// `part` is XORed with (row>>1)&3 on BOTH the producer and consumer side.
// gload_lds-staged tiles pre-swizzle the GLOBAL source (LDS dest stays linear);
// scalar-written tiles swizzle the write index. Reads use q ^ ((row>>1)&3).

// ---------------- quaternion block expansion helper ----------------
__device__ __forceinline__ void qexpand(const float* r, const float* i_, const float* j_,
                                        const float* k_, bf16* dst, int O4, int I4, int taps,
                                        int gid) {
  int C = 4 * I4;
  int o   = gid / (taps * C);
  int rem = gid % (taps * C);
  int tap = rem / C, c = rem % C;
  int br = o / O4, orr = o % O4, bc = c / I4, ic = c % I4;
  const float* srcs[4] = { r, i_, j_, k_ };
  const int   comp[4][4] = { {0,1,2,3}, {1,0,3,2}, {2,3,0,1}, {3,2,1,0} };
  const float sgn [4][4] = { {1,-1,-1,-1}, {1,1,-1,1}, {1,1,1,-1}, {1,-1,1,1} };
  float v = srcs[comp[br][bc]][(size_t)(orr * I4 + ic) * taps + tap];
  dst[gid] = __float2bfloat16(v * sgn[br][bc]);
}

// ---------------- one prep kernel: weight expansion + misc cvt + all zero-inits ----------------
#define N_W1 49152
#define N_W2 1327104
#define N_W3 16384
#define N_BR 396288
#define N_MI 900
#define N_SQ 512
#define N_SR 8192
#define N_PREP (N_W1 + N_W2 + N_W3 + N_BR + N_MI + N_SQ + N_SR)

__global__ void prep(const float* __restrict__ qr, const float* __restrict__ qi,
                     const float* __restrict__ qj, const float* __restrict__ qk,
                     const float* __restrict__ dr, const float* __restrict__ di,
                     const float* __restrict__ dj, const float* __restrict__ dk,
                     const float* __restrict__ pr, const float* __restrict__ pi,
                     const float* __restrict__ pj, const float* __restrict__ pk,
                     const float* __restrict__ qb, const float* __restrict__ db,
                     const float* __restrict__ pb, const float* __restrict__ tp,
                     bf16* __restrict__ W1t, bf16* __restrict__ W2t, bf16* __restrict__ W3t,
                     bf16* __restrict__ q1p, float* __restrict__ misc,
                     float* __restrict__ ssq, float* __restrict__ Sraw) {
  int gid = blockIdx.x * 256 + threadIdx.x;
  if (gid < N_W1) { qexpand(qr, qi, qj, qk, W1t, 96, 32, 1, gid); return; }
  gid -= N_W1;
  if (gid < N_W2) { qexpand(dr, di, dj, dk, W2t, 96, 96, 9, gid); return; }
  gid -= N_W2;
  if (gid < N_W3) { qexpand(pr, pi, pj, pk, W3t, 32, 32, 1, gid); return; }
  gid -= N_W3;
  if (gid < N_BR) {
    int b = gid / (516 * 384);
    int rem = gid % (516 * 384);
    int cell = rem / 384, c = rem % 384;
    int hp, wp;
    if      (cell < 130) { hp = 0;   wp = cell; }
    else if (cell < 260) { hp = 129; wp = cell - 130; }
    else if (cell < 388) { hp = cell - 260 + 1; wp = 0; }
    else                 { hp = cell - 388 + 1; wp = 129; }
    q1p[((size_t)((b * 130 + hp) * 130) + wp) * 384 + c] = __float2bfloat16(0.0f);
    return;
  }
  gid -= N_BR;
  if (gid < N_MI) {
    if (gid < 384)      misc[gid] = qb[gid];
    else if (gid < 768) misc[gid] = db[gid - 384];
    else if (gid < 896) misc[gid] = pb[gid - 768];
    else                misc[gid] = tp[gid - 896];
    return;
  }
  gid -= N_MI;
  if (gid < N_SQ) { ssq[gid] = 0.0f; return; }
  gid -= N_SQ;
  if (gid < N_SR) { Sraw[gid] = 0.0f; return; }
}

// ---------------- GEMM1 fused: x NCHW fp32 -> LDS transpose -> 3 o-tiles ----------------
__global__ __launch_bounds__(256) void gemm_qkv1f(const float* __restrict__ x,
                                                  const bf16* __restrict__ wt,
                                                  const float* __restrict__ bias,
                                                  bf16* __restrict__ out) {
  __shared__ __align__(16) bf16 Axl[4 * 64 * 32];   // [kchunk][w64][c32] 16 KB, swizzled
  __shared__ __align__(16) bf16 Bl [4 * 128 * 32];  // [kchunk][o][c32]  32 KB, swizzled
  const int h = blockIdx.x, wh = blockIdx.y, b = blockIdx.z;
  const int tid = threadIdx.x, wid = tid >> 6, lane = tid & 63;
  const int l16 = lane & 15, q = lane >> 4;
  const int sq8 = (q ^ ((l16 >> 1) & 3)) * 8;   // swizzled chunk offset for reads
  const int wm = (wid & 1) * 32, wn = (wid >> 1) * 64;
  {
    const int c = tid >> 1, seg = tid & 1;
    const float* src = x + ((size_t)(b * 128 + c) << 14) + h * 128 + wh * 64 + seg * 32;
    const int cb = (c >> 5) * 2048, c31 = c & 31;
    for (int j = 0; j < 8; ++j) {
      float4 v = *(const float4*)(src + j * 4);
      int w0 = seg * 32 + j * 4;
      float vv[4] = { v.x, v.y, v.z, v.w };
      for (int r = 0; r < 4; ++r) {
        int w = w0 + r;
        Axl[cb + w * 32 + (c31 ^ ((((w >> 1) & 3)) << 3))] = __float2bfloat16(vv[r]);
      }
    }
  }
  for (int ot = 0; ot < 3; ++ot) {
    __syncthreads();
    const bf16* bbase = wt + (size_t)ot * 16384;
    for (int i = 0; i < 8; ++i) {
      int ci = wid * 512 + i * 64 + lane;
      int chunk = ci >> 9, rem = ci & 511;
      int o = rem >> 2, part = rem & 3;
      int ps = part ^ ((o >> 1) & 3);
      gload_lds16(bbase + o * 128 + chunk * 32 + ps * 8, Bl + (size_t)(wid * 512 + i * 64) * 8);
    }
    __syncthreads();
    f32x4 acc[2][4] = {};
    for (int k = 0; k < 4; ++k) {
      bf16x8 af[2], bfr[4];
      for (int mi = 0; mi < 2; ++mi)
        af[mi] = *(const bf16x8*)&Axl[k * 2048 + (wm + mi * 16 + l16) * 32 + sq8];
      for (int ni = 0; ni < 4; ++ni)
        bfr[ni] = *(const bf16x8*)&Bl[k * 4096 + (wn + ni * 16 + l16) * 32 + sq8];
      for (int mi = 0; mi < 2; ++mi)
        for (int ni = 0; ni < 4; ++ni)
          acc[mi][ni] = __builtin_amdgcn_mfma_f32_16x16x32_bf16(af[mi], bfr[ni], acc[mi][ni], 0, 0, 0);
    }
    for (int ni = 0; ni < 4; ++ni) {
      int o = ot * 128 + wn + ni * 16 + l16;
      float bv = bias[o];
      for (int mi = 0; mi < 2; ++mi) {
        int w0 = wh * 64 + wm + mi * 16 + q * 4;
        for (int r = 0; r < 4; ++r) {
          int w = w0 + r;
          size_t idx = ((size_t)((b * 130 + h + 1) * 130) + (w + 1)) * 384 + o;
          out[idx] = __float2bfloat16(acc[mi][ni][r] + bv);
        }
      }
    }
    __syncthreads();
  }
}

// ---------------- conv2 v9: v7 geometry + LDS double-buffer + prefetch schedule ----------------
// Spill-free ni=3 (acc 96 VGPR). Dbuf A (2x50688) + B (2x27648) = 156672 B -> 1 block/CU,
// grid 512 (two rounds). Loop: STAGE(next) -> COMPUTE(cur) -> barrier. One barrier/stage;
// global loads for t+1 hide under the ~4200-cyc MFMA phase of t, so the barrier's vmcnt
// drain is ~free (v7 drained between stage and compute with nothing covering it).
// xcd=lid&7 -> b=xcd&1, hband=(xcd>>1)*32; slot=lid>>3 in [0,64):
//   h0 = hband + (slot&7)*4, ob = (slot>>3)*48, full 128 w. 216 MFMA/wave/stage.
// Swizzle: 16B chunk `part` XORed with (w>>1)&3 (A) / (o>>1)&3 (B) on global source;
// reads use q ^ ((row>>1)&3).
__global__ __launch_bounds__(256, 1) void conv3x3(const bf16* __restrict__ in,
                                                  const bf16* __restrict__ wt,
                                                  const float* __restrict__ bias,
                                                  bf16* __restrict__ out) {
  __shared__ __align__(16) short Al[2][6 * 132 * 32];   // 2 x 50688 B, swizzled
  __shared__ __align__(16) short Bl[2][9 * 48 * 32];    // 2 x 27648 B, swizzled
  const int lid = blockIdx.x;
  const int xcd = lid & 7, slot = lid >> 3;
  const int b = xcd & 1;
  const int h0 = (xcd >> 1) * 32 + (slot & 7) * 4;
  const int ob = (slot >> 3) * 48;
  const int tid = threadIdx.x, wid = tid >> 6, lane = tid & 63;
  const int l16 = lane & 15, q = lane >> 4;
  const int sA[3] = { (q ^ (((l16 + 0) >> 1) & 3)) * 8,
                      (q ^ (((l16 + 1) >> 1) & 3)) * 8,
                      (q ^ (((l16 + 2) >> 1) & 3)) * 8 };
  const int sB = sA[0];
  f32x4 acc[8][3] = {};
  const bf16* abase = in + (size_t)b * 130 * 130 * 384;
  const bf16* bbase = wt + (size_t)ob * 3456;

  auto stage = [&](int buf, int c0) {
    short* Ad = &Al[buf][0];
    short* Bd = &Bl[buf][0];
    // A: 3168 chunks (6 rows x 132 w x 4 parts); 792/wave = 12x64 + 24
    for (int i = 0; i < 12; ++i) {
      int g = wid * 792 + i * 64;
      int ci = g + lane;
      int row = ci / 528, rem = ci % 528;
      int w = rem >> 2, part = rem & 3;
      int ps = part ^ ((w >> 1) & 3);
      gload_lds16(abase + ((size_t)(h0 + row) * 130 + w) * 384 + c0 + ps * 8, Ad + g * 8);
    }
    if (lane < 24) {
      int g = wid * 792 + 768;
      int ci = g + lane;
      int row = ci / 528, rem = ci % 528;
      int w = rem >> 2, part = rem & 3;
      int ps = part ^ ((w >> 1) & 3);
      gload_lds16(abase + ((size_t)(h0 + row) * 130 + w) * 384 + c0 + ps * 8, Ad + g * 8);
    }
    // B: 1728 chunks (9 taps x 48 o x 4 parts); 432/wave = 6x64 + 48
    for (int i = 0; i < 6; ++i) {
      int g = wid * 432 + i * 64;
      int ci = g + lane;
      int tap = ci / 192, rem = ci % 192;
      int o = rem >> 2, part = rem & 3;
      int ps = part ^ ((o >> 1) & 3);
      gload_lds16(bbase + (size_t)o * 3456 + tap * 384 + c0 + ps * 8, Bd + g * 8);
    }
    if (lane < 48) {
      int g = wid * 432 + 384;
      int ci = g + lane;
      int tap = ci / 192, rem = ci % 192;
      int o = rem >> 2, part = rem & 3;
      int ps = part ^ ((o >> 1) & 3);
      gload_lds16(bbase + (size_t)o * 3456 + tap * 384 + c0 + ps * 8, Bd + g * 8);
    }
  };

  stage(0, 0);
  __syncthreads();
  for (int s = 0; s < 12; ++s) {
    const int cur = s & 1;
    if (s < 11) stage(cur ^ 1, (s + 1) * 32);
    for (int dh = 0; dh < 3; ++dh)
      for (int dw = 0; dw < 3; ++dw) {
        bf16x8 af[8], bfr[3];
        for (int mi = 0; mi < 8; ++mi)
          af[mi] = *(const bf16x8*)&Al[cur][((wid + dh) * 132 + mi * 16 + l16 + dw) * 32 + sA[dw]];
        for (int ni = 0; ni < 3; ++ni)
          bfr[ni] = *(const bf16x8*)&Bl[cur][((dh * 3 + dw) * 48 + ni * 16 + l16) * 32 + sB];
        for (int mi = 0; mi < 8; ++mi)
          for (int ni = 0; ni < 3; ++ni)
            acc[mi][ni] = __builtin_amdgcn_mfma_f32_16x16x32_bf16(af[mi], bfr[ni], acc[mi][ni], 0, 0, 0);
      }
    __syncthreads();
  }
  const int h = h0 + wid;
  for (int ni = 0; ni < 3; ++ni) {
    int o = ob + ni * 16 + l16;
    float bv = bias[o];
    for (int mi = 0; mi < 8; ++mi) {
      int w0 = mi * 16 + q * 4;
      for (int r = 0; r < 4; ++r) {
        int w = w0 + r;
        out[((size_t)(b * 16384 + h * 128 + w)) * 384 + o] = __float2bfloat16(acc[mi][ni][r] + bv);
      }
    }
  }
}

// ---------------- attn_qk + fused channel ssq (LDS-reduced atomics) ----------------
__global__ __launch_bounds__(256) void attn_qk(const bf16* __restrict__ q2,
                                               float* __restrict__ Sraw,
                                               float* __restrict__ ssq) {
  const int sc = blockIdx.x, h = blockIdx.y, b = blockIdx.z;
  const int t = threadIdx.x;
  __shared__ bf16 qt[64][32];
  __shared__ bf16 kt[64][32];
  __shared__ float Sl[1024];
  __shared__ float nql[32], nkl[32];
  for (int i = t; i < 1024; i += 256) Sl[i] = 0.0f;
  if (t < 32) nql[t] = 0.0f;
  else if (t < 64) nkl[t - 32] = 0.0f;
  const int slq = t >> 2, seg = t & 3;
  const int slot = t & 63, sg = t >> 6;
  const int cg = (slot & 7) * 4, dg = (slot >> 3) * 4;
  float acc[4][4] = {};
  float sq[4] = {}, sk[4] = {};
  for (int it = 0; it < 8; ++it) {
    int sbase = sc * 512 + it * 64;
    __syncthreads();
    {
      size_t rq = ((size_t)(b * 16384 + sbase + slq)) * 384 + h * 32 + seg * 8;
      *(bf16x8*)&qt[slq][seg * 8] = *(const bf16x8*)&q2[rq];
      *(bf16x8*)&kt[slq][seg * 8] = *(const bf16x8*)&q2[rq + 128];
    }
    __syncthreads();
    for (int sl = sg * 16; sl < sg * 16 + 16; ++sl) {
      float qv[4], kv[4];
      for (int a = 0; a < 4; ++a) qv[a] = __bfloat162float(qt[sl][cg + a]);
      for (int d = 0; d < 4; ++d) kv[d] = __bfloat162float(kt[sl][dg + d]);
      if (dg == 0) for (int a = 0; a < 4; ++a) sq[a] += qv[a] * qv[a];
      if (cg == 0) for (int d = 0; d < 4; ++d) sk[d] += kv[d] * kv[d];
      for (int a = 0; a < 4; ++a)
        for (int d = 0; d < 4; ++d) acc[a][d] += qv[a] * kv[d];
    }
  }
  for (int a = 0; a < 4; ++a)
    for (int d = 0; d < 4; ++d)
      atomicAdd(&Sl[(cg + a) * 32 + dg + d], acc[a][d]);
  if (dg == 0) for (int a = 0; a < 4; ++a) atomicAdd(&nql[cg + a], sq[a]);
  if (cg == 0) for (int d = 0; d < 4; ++d) atomicAdd(&nkl[dg + d], sk[d]);
  __syncthreads();
  float* Sg = Sraw + (size_t)((b * 4 + h) * 1024);
  for (int i = t * 4; i < t * 4 + 4; ++i) atomicAdd(&Sg[i], Sl[i]);
  if (t < 32) atomicAdd(&ssq[b * 256 + h * 32 + t], nql[t]);
  else if (t < 64) atomicAdd(&ssq[b * 256 + 128 + h * 32 + (t - 32)], nkl[t - 32]);
}

// ---------------- attn_out: softmax -> M = W3.blockdiag(P) in LDS -> GEMM vs v -> d_out ----------------
__global__ __launch_bounds__(256) void attn_out(const bf16* __restrict__ q2,
                                                const float* __restrict__ Sraw,
                                                const float* __restrict__ ssq,
                                                const float* __restrict__ misc,
                                                const bf16* __restrict__ w3,
                                                float* __restrict__ out) {
  __shared__ __align__(16) bf16 Ml[4 * 128 * 32];   // 32 KB [kchunk][o][c32], swizzled
  __shared__ float Pl[4][32][32];                    // 16 KB
  __shared__ __align__(16) short Bl[128 * 32];       // 8 KB v-stage, swizzled
  __shared__ float rqa[128], rka[128];
  const int tile = blockIdx.x;
  const int b = tile >> 7, s0 = (tile & 127) * 128;
  const int t = threadIdx.x;
  const int wid = t >> 6, lane = t & 63;
  const int l16 = lane & 15, q = lane >> 4;
  const int sq8 = (q ^ ((l16 >> 1) & 3)) * 8;
  {
    float v = ssq[b * 256 + t];
    float rv = 1.0f / fmaxf(sqrtf(fmaxf(v, 0.0f)), 1e-12f);
    if (t < 128) rqa[t] = rv; else rka[t - 128] = rv;
  }
  __syncthreads();
  if (t < 128) {
    int hh = t >> 5, c = t & 31;
    const float* Sr = Sraw + ((size_t)((b * 4 + hh) * 32 + c)) * 32;
    float tv = misc[896 + hh];
    float rq = rqa[t];
    float row[32];
    float m = -1e30f;
    for (int d = 0; d < 32; ++d) { row[d] = Sr[d] * tv * rq * rka[hh * 32 + d]; m = fmaxf(m, row[d]); }
    float sum = 0.0f;
    for (int d = 0; d < 32; ++d) { row[d] = expf(row[d] - m); sum += row[d]; }
    float inv = 1.0f / sum;
    for (int d = 0; d < 32; ++d) Pl[hh][c][d] = row[d] * inv;
  }
  __syncthreads();
  {
    const int o = t >> 1, half = t & 1;
    const int sw = ((o >> 1) & 3) << 3;   // swizzle for Ml writes (rows = o, 64B stride)
    for (int hh2 = 0; hh2 < 2; ++hh2) {
      int hv = half * 2 + hh2;
      float w3r[32];
      const bf16* wrow = w3 + o * 128 + hv * 32;
      for (int c = 0; c < 32; ++c) w3r[c] = __bfloat162float(wrow[c]);
      for (int d = 0; d < 32; ++d) {
        float s = 0.0f;
        for (int c = 0; c < 32; ++c) s += w3r[c] * Pl[hv][c][d];
        Ml[hv * 4096 + o * 32 + (d ^ sw)] = __float2bfloat16(s);
      }
    }
  }
  f32x4 acc[4][4] = {};
  const int wmo = (wid & 1) * 64, wns = (wid >> 1) * 64;
  for (int kc = 0; kc < 4; ++kc) {
    __syncthreads();
    for (int i = 0; i < 2; ++i) {
      int ci = i * 256 + t;
      int s = ci >> 2, part = ci & 3;
      int ps = part ^ ((s >> 1) & 3);
      gload_lds16(q2 + ((size_t)(b * 16384 + s0 + s)) * 384 + 256 + kc * 32 + ps * 8,
                  &Bl[(size_t)(i * 256 + wid * 64) * 8]);
    }
    __syncthreads();
    bf16x8 af[4], bfr[4];
    for (int mi = 0; mi < 4; ++mi)
      af[mi] = *(const bf16x8*)&Ml[kc * 4096 + (wmo + mi * 16 + l16) * 32 + sq8];
    for (int ni = 0; ni < 4; ++ni)
      bfr[ni] = *(const bf16x8*)&Bl[(wns + ni * 16 + l16) * 32 + sq8];
    for (int mi = 0; mi < 4; ++mi)
      for (int ni = 0; ni < 4; ++ni)
        acc[mi][ni] = __builtin_amdgcn_mfma_f32_16x16x32_bf16(af[mi], bfr[ni], acc[mi][ni], 0, 0, 0);
  }
  for (int ni = 0; ni < 4; ++ni) {
    int s = s0 + wns + ni * 16 + l16;
    for (int mi = 0; mi < 4; ++mi) {
      int o0 = wmo + mi * 16 + q * 4;
      for (int r = 0; r < 4; ++r) {
        int o = o0 + r;
        out[(size_t)b * 2097152 + (size_t)o * 16384 + s] = acc[mi][ni][r] + misc[768 + o];
      }
    }
  }
}

extern "C" void kernel_launch(void* const* d_in, const int* in_sizes, int n_in,
                              void* d_out, int out_size, void* d_ws, size_t ws_size,
                              hipStream_t stream) {
  const float* x     = (const float*)d_in[0];
  const float* qkv_r = (const float*)d_in[1];
  const float* qkv_i = (const float*)d_in[2];
  const float* qkv_j = (const float*)d_in[3];
  const float* qkv_k = (const float*)d_in[4];
  const float* qkv_b = (const float*)d_in[5];
  const float* dw_r  = (const float*)d_in[6];
  const float* dw_i  = (const float*)d_in[7];
  const float* dw_j  = (const float*)d_in[8];
  const float* dw_k  = (const float*)d_in[9];
  const float* dw_b  = (const float*)d_in[10];
  const float* po_r  = (const float*)d_in[11];
  const float* po_i  = (const float*)d_in[12];
  const float* po_j  = (const float*)d_in[13];
  const float* po_k  = (const float*)d_in[14];
  const float* po_b  = (const float*)d_in[15];
  const float* temp  = (const float*)d_in[16];

  char* ws = (char*)d_ws;
  size_t off = 0;
  auto alloc = [&](size_t bytes) { char* p = ws + off; off += (bytes + 255) & ~(size_t)255; return p; };
  bf16* q1p  = (bf16*)alloc((size_t)2 * 130 * 130 * 384 * 2);
  bf16* q2   = (bf16*)alloc((size_t)2 * 16384 * 384 * 2);
  bf16* W1t  = (bf16*)alloc((size_t)384 * 128 * 2);
  bf16* W2t  = (bf16*)alloc((size_t)384 * 3456 * 2);
  bf16* W3t  = (bf16*)alloc((size_t)128 * 128 * 2);
  float* ssq  = (float*)alloc((size_t)2 * 256 * 4);
  float* Sraw = (float*)alloc((size_t)2 * 4 * 32 * 32 * 4);
  float* misc = (float*)alloc((size_t)900 * 4);

  prep<<<(N_PREP + 255) / 256, 256, 0, stream>>>(qkv_r, qkv_i, qkv_j, qkv_k,
                                                 dw_r, dw_i, dw_j, dw_k,
                                                 po_r, po_i, po_j, po_k,
                                                 qkv_b, dw_b, po_b, temp,
                                                 W1t, W2t, W3t, q1p, misc, ssq, Sraw);
  gemm_qkv1f<<<dim3(128, 2, 2), 256, 0, stream>>>(x, W1t, misc, q1p);
  conv3x3<<<512, 256, 0, stream>>>(q1p, W2t, misc + 384, q2);
  attn_qk<<<dim3(32, 4, 2), 256, 0, stream>>>(q2, Sraw, ssq);
  attn_out<<<256, 256, 0, stream>>>(q2, Sraw, ssq, misc, W3t, (float*)d_out);
}

// Round 4
// 217.733 us; speedup vs baseline: 1.1722x; 1.1722x over previous
//
#include <hip/hip_runtime.h>
#include <hip/hip_bf16.h>
#include <string.h>

typedef __hip_bfloat16 bf16;
typedef __bf16 bf16x8 __attribute__((ext_vector_type(8)));
typedef float f32x4 __attribute__((ext_vector_type(4)));

typedef __attribute__((address_space(1))) void* gas_ptr;
typedef __attribute__((address_space(3))) void* las_ptr;

__device__ __forceinline__ void gload_lds16(const void* g, void* l) {
  __builtin_amdgcn_global_load_lds((gas_ptr)(void*)g, (las_ptr)l, 16, 0, 0);
}

// Inputs confirmed fp32 (rounds 2-8 passed with fp32 path).
// T2 swizzle convention for [row][32ch] bf16 tiles (64B rows): 16B-chunk index
// `part` is XORed with (row>>1)&3 on BOTH the producer and consumer side.
// HARD CONSTRAINT (R2/R3 lesson): conv3x3 needs >=2 waves/SIMD (LDS <= 80KB/block);
// 1 block/CU variants lose 2x to exposed ds_read->MFMA latency regardless of schedule.

// ---------------- quaternion block expansion helper ----------------
__device__ __forceinline__ void qexpand(const float* r, const float* i_, const float* j_,
                                        const float* k_, bf16* dst, int O4, int I4, int taps,
                                        int gid) {
  int C = 4 * I4;
  int o   = gid / (taps * C);
  int rem = gid % (taps * C);
  int tap = rem / C, c = rem % C;
  int br = o / O4, orr = o % O4, bc = c / I4, ic = c % I4;
  const float* srcs[4] = { r, i_, j_, k_ };
  const int   comp[4][4] = { {0,1,2,3}, {1,0,3,2}, {2,3,0,1}, {3,2,1,0} };
  const float sgn [4][4] = { {1,-1,-1,-1}, {1,1,-1,1}, {1,1,1,-1}, {1,-1,1,1} };
  float v = srcs[comp[br][bc]][(size_t)(orr * I4 + ic) * taps + tap];
  dst[gid] = __float2bfloat16(v * sgn[br][bc]);
}

// ---------------- one prep kernel: weight expansion + misc cvt + all zero-inits ----------------
#define N_W1 49152
#define N_W2 1327104
#define N_W3 16384
#define N_BR 396288
#define N_MI 900
#define N_SQ 512
#define N_SR 8192
#define N_PREP (N_W1 + N_W2 + N_W3 + N_BR + N_MI + N_SQ + N_SR)

__global__ void prep(const float* __restrict__ qr, const float* __restrict__ qi,
                     const float* __restrict__ qj, const float* __restrict__ qk,
                     const float* __restrict__ dr, const float* __restrict__ di,
                     const float* __restrict__ dj, const float* __restrict__ dk,
                     const float* __restrict__ pr, const float* __restrict__ pi,
                     const float* __restrict__ pj, const float* __restrict__ pk,
                     const float* __restrict__ qb, const float* __restrict__ db,
                     const float* __restrict__ pb, const float* __restrict__ tp,
                     bf16* __restrict__ W1t, bf16* __restrict__ W2t, bf16* __restrict__ W3t,
                     bf16* __restrict__ q1p, float* __restrict__ misc,
                     float* __restrict__ ssq, float* __restrict__ Sraw) {
  int gid = blockIdx.x * 256 + threadIdx.x;
  if (gid < N_W1) { qexpand(qr, qi, qj, qk, W1t, 96, 32, 1, gid); return; }
  gid -= N_W1;
  if (gid < N_W2) { qexpand(dr, di, dj, dk, W2t, 96, 96, 9, gid); return; }
  gid -= N_W2;
  if (gid < N_W3) { qexpand(pr, pi, pj, pk, W3t, 32, 32, 1, gid); return; }
  gid -= N_W3;
  if (gid < N_BR) {
    int b = gid / (516 * 384);
    int rem = gid % (516 * 384);
    int cell = rem / 384, c = rem % 384;
    int hp, wp;
    if      (cell < 130) { hp = 0;   wp = cell; }
    else if (cell < 260) { hp = 129; wp = cell - 130; }
    else if (cell < 388) { hp = cell - 260 + 1; wp = 0; }
    else                 { hp = cell - 388 + 1; wp = 129; }
    q1p[((size_t)((b * 130 + hp) * 130) + wp) * 384 + c] = __float2bfloat16(0.0f);
    return;
  }
  gid -= N_BR;
  if (gid < N_MI) {
    if (gid < 384)      misc[gid] = qb[gid];
    else if (gid < 768) misc[gid] = db[gid - 384];
    else if (gid < 896) misc[gid] = pb[gid - 768];
    else                misc[gid] = tp[gid - 896];
    return;
  }
  gid -= N_MI;
  if (gid < N_SQ) { ssq[gid] = 0.0f; return; }
  gid -= N_SQ;
  if (gid < N_SR) { Sraw[gid] = 0.0f; return; }
}

// ---------------- GEMM1 fused: x NCHW fp32 -> LDS transpose -> 3 o-tiles ----------------
__global__ __launch_bounds__(256) void gemm_qkv1f(const float* __restrict__ x,
                                                  const bf16* __restrict__ wt,
                                                  const float* __restrict__ bias,
                                                  bf16* __restrict__ out) {
  __shared__ __align__(16) bf16 Axl[4 * 64 * 32];   // [kchunk][w64][c32] 16 KB, swizzled
  __shared__ __align__(16) bf16 Bl [4 * 128 * 32];  // [kchunk][o][c32]  32 KB, swizzled
  const int h = blockIdx.x, wh = blockIdx.y, b = blockIdx.z;
  const int tid = threadIdx.x, wid = tid >> 6, lane = tid & 63;
  const int l16 = lane & 15, q = lane >> 4;
  const int sq8 = (q ^ ((l16 >> 1) & 3)) * 8;   // swizzled chunk offset for reads
  const int wm = (wid & 1) * 32, wn = (wid >> 1) * 64;
  {
    const int c = tid >> 1, seg = tid & 1;
    const float* src = x + ((size_t)(b * 128 + c) << 14) + h * 128 + wh * 64 + seg * 32;
    const int cb = (c >> 5) * 2048, c31 = c & 31;
    for (int j = 0; j < 8; ++j) {
      float4 v = *(const float4*)(src + j * 4);
      int w0 = seg * 32 + j * 4;
      float vv[4] = { v.x, v.y, v.z, v.w };
      for (int r = 0; r < 4; ++r) {
        int w = w0 + r;
        Axl[cb + w * 32 + (c31 ^ ((((w >> 1) & 3)) << 3))] = __float2bfloat16(vv[r]);
      }
    }
  }
  for (int ot = 0; ot < 3; ++ot) {
    __syncthreads();
    const bf16* bbase = wt + (size_t)ot * 16384;
    for (int i = 0; i < 8; ++i) {
      int ci = wid * 512 + i * 64 + lane;
      int chunk = ci >> 9, rem = ci & 511;
      int o = rem >> 2, part = rem & 3;
      int ps = part ^ ((o >> 1) & 3);
      gload_lds16(bbase + o * 128 + chunk * 32 + ps * 8, Bl + (size_t)(wid * 512 + i * 64) * 8);
    }
    __syncthreads();
    f32x4 acc[2][4] = {};
    for (int k = 0; k < 4; ++k) {
      bf16x8 af[2], bfr[4];
      for (int mi = 0; mi < 2; ++mi)
        af[mi] = *(const bf16x8*)&Axl[k * 2048 + (wm + mi * 16 + l16) * 32 + sq8];
      for (int ni = 0; ni < 4; ++ni)
        bfr[ni] = *(const bf16x8*)&Bl[k * 4096 + (wn + ni * 16 + l16) * 32 + sq8];
      for (int mi = 0; mi < 2; ++mi)
        for (int ni = 0; ni < 4; ++ni)
          acc[mi][ni] = __builtin_amdgcn_mfma_f32_16x16x32_bf16(af[mi], bfr[ni], acc[mi][ni], 0, 0, 0);
    }
    for (int ni = 0; ni < 4; ++ni) {
      int o = ot * 128 + wn + ni * 16 + l16;
      float bv = bias[o];
      for (int mi = 0; mi < 2; ++mi) {
        int w0 = wh * 64 + wm + mi * 16 + q * 4;
        for (int r = 0; r < 4; ++r) {
          int w = w0 + r;
          size_t idx = ((size_t)((b * 130 + h + 1) * 130) + (w + 1)) * 384 + o;
          out[idx] = __float2bfloat16(acc[mi][ni][r] + bv);
        }
      }
    }
    __syncthreads();
  }
}

// ---------------- conv2 v7 (reverted: proven 78.8 us, 2 blocks/CU) ----------------
// xcd=lid&7 -> b=xcd&1, hband=(xcd>>1)*32; slot=lid>>3 in [0,64):
//   h0 = hband + (slot&7)*4, ob = (slot>>3)*48, full 128 w. 216 MFMA/wave/stage.
// Per c0 (12 stages): A = 6 rows x 132 w x 32c (50.7 KB), B = 9 taps x 48 o x 32c (27.6 KB).
// Swizzle: 16B chunk `part` XORed with (w>>1)&3 (A) / (o>>1)&3 (B) on the global source;
// reads use q ^ ((row>>1)&3).
__global__ __launch_bounds__(256, 2) void conv3x3(const bf16* __restrict__ in,
                                                  const bf16* __restrict__ wt,
                                                  const float* __restrict__ bias,
                                                  bf16* __restrict__ out) {
  __shared__ __align__(16) short Al[6 * 132 * 32];   // 50688 B, chunk-contiguous, swizzled
  __shared__ __align__(16) short Bl[9 * 48 * 32];    // 27648 B, swizzled
  const int lid = blockIdx.x;
  const int xcd = lid & 7, slot = lid >> 3;
  const int b = xcd & 1;
  const int h0 = (xcd >> 1) * 32 + (slot & 7) * 4;
  const int ob = (slot >> 3) * 48;
  const int tid = threadIdx.x, wid = tid >> 6, lane = tid & 63;
  const int l16 = lane & 15, q = lane >> 4;
  const int sA[3] = { (q ^ (((l16 + 0) >> 1) & 3)) * 8,
                      (q ^ (((l16 + 1) >> 1) & 3)) * 8,
                      (q ^ (((l16 + 2) >> 1) & 3)) * 8 };
  const int sB = sA[0];
  f32x4 acc[8][3] = {};
  const bf16* abase = in + (size_t)b * 130 * 130 * 384;
  const bf16* bbase = wt + (size_t)ob * 3456;
  for (int c0 = 0; c0 < 384; c0 += 32) {
    __syncthreads();
    // A: 3168 chunks (6 rows x 132 w x 4 parts); 792/wave = 12x64 + 24
    for (int i = 0; i < 12; ++i) {
      int g = wid * 792 + i * 64;
      int ci = g + lane;
      int row = ci / 528, rem = ci % 528;
      int w = rem >> 2, part = rem & 3;
      int ps = part ^ ((w >> 1) & 3);
      gload_lds16(abase + ((size_t)(h0 + row) * 130 + w) * 384 + c0 + ps * 8, &Al[g * 8]);
    }
    if (lane < 24) {
      int g = wid * 792 + 768;
      int ci = g + lane;
      int row = ci / 528, rem = ci % 528;
      int w = rem >> 2, part = rem & 3;
      int ps = part ^ ((w >> 1) & 3);
      gload_lds16(abase + ((size_t)(h0 + row) * 130 + w) * 384 + c0 + ps * 8, &Al[g * 8]);
    }
    // B: 1728 chunks (9 taps x 48 o x 4 parts); 432/wave = 6x64 + 48
    for (int i = 0; i < 6; ++i) {
      int g = wid * 432 + i * 64;
      int ci = g + lane;
      int tap = ci / 192, rem = ci % 192;
      int o = rem >> 2, part = rem & 3;
      int ps = part ^ ((o >> 1) & 3);
      gload_lds16(bbase + (size_t)o * 3456 + tap * 384 + c0 + ps * 8, &Bl[g * 8]);
    }
    if (lane < 48) {
      int g = wid * 432 + 384;
      int ci = g + lane;
      int tap = ci / 192, rem = ci % 192;
      int o = rem >> 2, part = rem & 3;
      int ps = part ^ ((o >> 1) & 3);
      gload_lds16(bbase + (size_t)o * 3456 + tap * 384 + c0 + ps * 8, &Bl[g * 8]);
    }
    __syncthreads();
    for (int dh = 0; dh < 3; ++dh)
      for (int dw = 0; dw < 3; ++dw) {
        bf16x8 af[8], bfr[3];
        for (int mi = 0; mi < 8; ++mi)
          af[mi] = *(const bf16x8*)&Al[((wid + dh) * 132 + mi * 16 + l16 + dw) * 32 + sA[dw]];
        for (int ni = 0; ni < 3; ++ni)
          bfr[ni] = *(const bf16x8*)&Bl[((dh * 3 + dw) * 48 + ni * 16 + l16) * 32 + sB];
        for (int mi = 0; mi < 8; ++mi)
          for (int ni = 0; ni < 3; ++ni)
            acc[mi][ni] = __builtin_amdgcn_mfma_f32_16x16x32_bf16(af[mi], bfr[ni], acc[mi][ni], 0, 0, 0);
      }
  }
  const int h = h0 + wid;
  for (int ni = 0; ni < 3; ++ni) {
    int o = ob + ni * 16 + l16;
    float bv = bias[o];
    for (int mi = 0; mi < 8; ++mi) {
      int w0 = mi * 16 + q * 4;
      for (int r = 0; r < 4; ++r) {
        int w = w0 + r;
        out[((size_t)(b * 16384 + h * 128 + w)) * 384 + o] = __float2bfloat16(acc[mi][ni][r] + bv);
      }
    }
  }
}

// ---------------- attn_qk v2: MFMA. S = q.k^T, ssq via qq^T/kk^T diag tiles ----------------
// Per block (sc,h,b): 512-s slab. Stage q,k transposed to LDS qkT[64 ch][512 s] (bf16),
// via register 8x8 transpose + ds_write_b128. Swizzle: 16B-chunk index XOR (row^(row>>3))&7
// -> both the write phase (rows vary by 8) and read phase (rows vary by 1) hit the optimal
// 8-lanes-per-slot distribution. Each wave: 128-s subrange, 4 K-steps.
// S tiles: mfma(afq[ct], afk[dt]) (A/B frags have identical lane layout for row-major .
// row-major^T). ssq: mfma(afq,afq)/(afk,afk) diag tiles, extract lane-diagonal.
__global__ __launch_bounds__(256) void attn_qk(const bf16* __restrict__ q2,
                                               float* __restrict__ Sraw,
                                               float* __restrict__ ssq) {
  const int sc = blockIdx.x, h = blockIdx.y, b = blockIdx.z;
  const int t = threadIdx.x;
  __shared__ __align__(16) short qkT[64 * 512];   // 64 KB: rows 0..31 = q ch, 32..63 = k ch
  __shared__ float Sl[1024];
  __shared__ float nql[32], nkl[32];
  for (int i = t; i < 1024; i += 256) Sl[i] = 0.0f;
  if (t < 32) nql[t] = 0.0f;
  else if (t < 64) nkl[t - 32] = 0.0f;
  const int ch8 = t & 7, sg = t >> 3;
  const int goff = (ch8 < 4) ? (h * 32 + ch8 * 8) : (128 + h * 32 + (ch8 - 4) * 8);
  const int S0 = sc * 512;
  for (int p = 0; p < 2; ++p) {
    int schunk = sg + p * 32;
    const bf16* src = q2 + (size_t)(b * 16384 + S0 + schunk * 8) * 384 + goff;
    bf16x8 ld[8];
#pragma unroll
    for (int s = 0; s < 8; ++s) ld[s] = *(const bf16x8*)(src + (size_t)s * 384);
#pragma unroll
    for (int j = 0; j < 8; ++j) {
      bf16x8 wv;
#pragma unroll
      for (int s = 0; s < 8; ++s) wv[s] = ld[s][j];
      int row = ch8 * 8 + j;
      int sw = (row ^ (row >> 3)) & 7;
      *(bf16x8*)&qkT[row * 512 + (schunk ^ sw) * 8] = wv;
    }
  }
  __syncthreads();
  const int wid = t >> 6, lane = t & 63;
  const int l16 = lane & 15, q = lane >> 4;
  f32x4 Sacc[2][2] = {};
  f32x4 qqa[2] = {}, kka[2] = {};
  for (int it = 0; it < 4; ++it) {
    int chunkR = wid * 16 + it * 4 + q;
    bf16x8 afq[2], afk[2];
#pragma unroll
    for (int ct = 0; ct < 2; ++ct) {
      int rq = ct * 16 + l16;
      afq[ct] = *(const bf16x8*)&qkT[rq * 512 + (chunkR ^ ((rq ^ (rq >> 3)) & 7)) * 8];
      int rk = 32 + ct * 16 + l16;
      afk[ct] = *(const bf16x8*)&qkT[rk * 512 + (chunkR ^ ((rk ^ (rk >> 3)) & 7)) * 8];
    }
#pragma unroll
    for (int ct = 0; ct < 2; ++ct)
#pragma unroll
      for (int dt = 0; dt < 2; ++dt)
        Sacc[ct][dt] = __builtin_amdgcn_mfma_f32_16x16x32_bf16(afq[ct], afk[dt], Sacc[ct][dt], 0, 0, 0);
#pragma unroll
    for (int ct = 0; ct < 2; ++ct) {
      qqa[ct] = __builtin_amdgcn_mfma_f32_16x16x32_bf16(afq[ct], afq[ct], qqa[ct], 0, 0, 0);
      kka[ct] = __builtin_amdgcn_mfma_f32_16x16x32_bf16(afk[ct], afk[ct], kka[ct], 0, 0, 0);
    }
  }
#pragma unroll
  for (int ct = 0; ct < 2; ++ct)
#pragma unroll
    for (int dt = 0; dt < 2; ++dt)
#pragma unroll
      for (int r = 0; r < 4; ++r)
        atomicAdd(&Sl[(ct * 16 + q * 4 + r) * 32 + dt * 16 + l16], Sacc[ct][dt][r]);
  if ((l16 >> 2) == q) {
    int r = l16 & 3;
#pragma unroll
    for (int ct = 0; ct < 2; ++ct) {
      float vq = r == 0 ? qqa[ct][0] : r == 1 ? qqa[ct][1] : r == 2 ? qqa[ct][2] : qqa[ct][3];
      float vk = r == 0 ? kka[ct][0] : r == 1 ? kka[ct][1] : r == 2 ? kka[ct][2] : kka[ct][3];
      atomicAdd(&nql[ct * 16 + l16], vq);
      atomicAdd(&nkl[ct * 16 + l16], vk);
    }
  }
  __syncthreads();
  float* Sg = Sraw + (size_t)((b * 4 + h) * 1024);
  for (int i = t * 4; i < t * 4 + 4; ++i) atomicAdd(&Sg[i], Sl[i]);
  if (t < 32) atomicAdd(&ssq[b * 256 + h * 32 + t], nql[t]);
  else if (t < 64) atomicAdd(&ssq[b * 256 + 128 + h * 32 + (t - 32)], nkl[t - 32]);
}

// ---------------- attn_out: softmax -> M = W3.blockdiag(P) in LDS -> GEMM vs v -> d_out ----------------
__global__ __launch_bounds__(256) void attn_out(const bf16* __restrict__ q2,
                                                const float* __restrict__ Sraw,
                                                const float* __restrict__ ssq,
                                                const float* __restrict__ misc,
                                                const bf16* __restrict__ w3,
                                                float* __restrict__ out) {
  __shared__ __align__(16) bf16 Ml[4 * 128 * 32];   // 32 KB [kchunk][o][c32], swizzled
  __shared__ float Pl[4][32][32];                    // 16 KB
  __shared__ __align__(16) short Bl[128 * 32];       // 8 KB v-stage, swizzled
  __shared__ float rqa[128], rka[128];
  const int tile = blockIdx.x;
  const int b = tile >> 7, s0 = (tile & 127) * 128;
  const int t = threadIdx.x;
  const int wid = t >> 6, lane = t & 63;
  const int l16 = lane & 15, q = lane >> 4;
  const int sq8 = (q ^ ((l16 >> 1) & 3)) * 8;
  {
    float v = ssq[b * 256 + t];
    float rv = 1.0f / fmaxf(sqrtf(fmaxf(v, 0.0f)), 1e-12f);
    if (t < 128) rqa[t] = rv; else rka[t - 128] = rv;
  }
  __syncthreads();
  if (t < 128) {
    int hh = t >> 5, c = t & 31;
    const float* Sr = Sraw + ((size_t)((b * 4 + hh) * 32 + c)) * 32;
    float tv = misc[896 + hh];
    float rq = rqa[t];
    float row[32];
    float m = -1e30f;
    for (int d = 0; d < 32; ++d) { row[d] = Sr[d] * tv * rq * rka[hh * 32 + d]; m = fmaxf(m, row[d]); }
    float sum = 0.0f;
    for (int d = 0; d < 32; ++d) { row[d] = expf(row[d] - m); sum += row[d]; }
    float inv = 1.0f / sum;
    for (int d = 0; d < 32; ++d) Pl[hh][c][d] = row[d] * inv;
  }
  __syncthreads();
  {
    const int o = t >> 1, half = t & 1;
    const int sw = ((o >> 1) & 3) << 3;   // swizzle for Ml writes (rows = o, 64B stride)
    for (int hh2 = 0; hh2 < 2; ++hh2) {
      int hv = half * 2 + hh2;
      float w3r[32];
      const bf16* wrow = w3 + o * 128 + hv * 32;
      for (int c = 0; c < 32; ++c) w3r[c] = __bfloat162float(wrow[c]);
      for (int d = 0; d < 32; ++d) {
        float s = 0.0f;
        for (int c = 0; c < 32; ++c) s += w3r[c] * Pl[hv][c][d];
        Ml[hv * 4096 + o * 32 + (d ^ sw)] = __float2bfloat16(s);
      }
    }
  }
  f32x4 acc[4][4] = {};
  const int wmo = (wid & 1) * 64, wns = (wid >> 1) * 64;
  for (int kc = 0; kc < 4; ++kc) {
    __syncthreads();
    for (int i = 0; i < 2; ++i) {
      int ci = i * 256 + t;
      int s = ci >> 2, part = ci & 3;
      int ps = part ^ ((s >> 1) & 3);
      gload_lds16(q2 + ((size_t)(b * 16384 + s0 + s)) * 384 + 256 + kc * 32 + ps * 8,
                  &Bl[(size_t)(i * 256 + wid * 64) * 8]);
    }
    __syncthreads();
    bf16x8 af[4], bfr[4];
    for (int mi = 0; mi < 4; ++mi)
      af[mi] = *(const bf16x8*)&Ml[kc * 4096 + (wmo + mi * 16 + l16) * 32 + sq8];
    for (int ni = 0; ni < 4; ++ni)
      bfr[ni] = *(const bf16x8*)&Bl[(wns + ni * 16 + l16) * 32 + sq8];
    for (int mi = 0; mi < 4; ++mi)
      for (int ni = 0; ni < 4; ++ni)
        acc[mi][ni] = __builtin_amdgcn_mfma_f32_16x16x32_bf16(af[mi], bfr[ni], acc[mi][ni], 0, 0, 0);
  }
  for (int ni = 0; ni < 4; ++ni) {
    int s = s0 + wns + ni * 16 + l16;
    for (int mi = 0; mi < 4; ++mi) {
      int o0 = wmo + mi * 16 + q * 4;
      for (int r = 0; r < 4; ++r) {
        int o = o0 + r;
        out[(size_t)b * 2097152 + (size_t)o * 16384 + s] = acc[mi][ni][r] + misc[768 + o];
      }
    }
  }
}

extern "C" void kernel_launch(void* const* d_in, const int* in_sizes, int n_in,
                              void* d_out, int out_size, void* d_ws, size_t ws_size,
                              hipStream_t stream) {
  const float* x     = (const float*)d_in[0];
  const float* qkv_r = (const float*)d_in[1];
  const float* qkv_i = (const float*)d_in[2];
  const float* qkv_j = (const float*)d_in[3];
  const float* qkv_k = (const float*)d_in[4];
  const float* qkv_b = (const float*)d_in[5];
  const float* dw_r  = (const float*)d_in[6];
  const float* dw_i  = (const float*)d_in[7];
  const float* dw_j  = (const float*)d_in[8];
  const float* dw_k  = (const float*)d_in[9];
  const float* dw_b  = (const float*)d_in[10];
  const float* po_r  = (const float*)d_in[11];
  const float* po_i  = (const float*)d_in[12];
  const float* po_j  = (const float*)d_in[13];
  const float* po_k  = (const float*)d_in[14];
  const float* po_b  = (const float*)d_in[15];
  const float* temp  = (const float*)d_in[16];

  char* ws = (char*)d_ws;
  size_t off = 0;
  auto alloc = [&](size_t bytes) { char* p = ws + off; off += (bytes + 255) & ~(size_t)255; return p; };
  bf16* q1p  = (bf16*)alloc((size_t)2 * 130 * 130 * 384 * 2);
  bf16* q2   = (bf16*)alloc((size_t)2 * 16384 * 384 * 2);
  bf16* W1t  = (bf16*)alloc((size_t)384 * 128 * 2);
  bf16* W2t  = (bf16*)alloc((size_t)384 * 3456 * 2);
  bf16* W3t  = (bf16*)alloc((size_t)128 * 128 * 2);
  float* ssq  = (float*)alloc((size_t)2 * 256 * 4);
  float* Sraw = (float*)alloc((size_t)2 * 4 * 32 * 32 * 4);
  float* misc = (float*)alloc((size_t)900 * 4);

  prep<<<(N_PREP + 255) / 256, 256, 0, stream>>>(qkv_r, qkv_i, qkv_j, qkv_k,
                                                 dw_r, dw_i, dw_j, dw_k,
                                                 po_r, po_i, po_j, po_k,
                                                 qkv_b, dw_b, po_b, temp,
                                                 W1t, W2t, W3t, q1p, misc, ssq, Sraw);
  gemm_qkv1f<<<dim3(128, 2, 2), 256, 0, stream>>>(x, W1t, misc, q1p);
  conv3x3<<<512, 256, 0, stream>>>(q1p, W2t, misc + 384, q2);
  attn_qk<<<dim3(32, 4, 2), 256, 0, stream>>>(q2, Sraw, ssq);
  attn_out<<<256, 256, 0, stream>>>(q2, Sraw, ssq, misc, W3t, (float*)d_out);
}

// Round 5
// 203.359 us; speedup vs baseline: 1.2550x; 1.0707x over previous
//
#include <hip/hip_runtime.h>
#include <hip/hip_bf16.h>
#include <string.h>

typedef __hip_bfloat16 bf16;
typedef __bf16 bf16x8 __attribute__((ext_vector_type(8)));
typedef float f32x4 __attribute__((ext_vector_type(4)));

typedef __attribute__((address_space(1))) void* gas_ptr;
typedef __attribute__((address_space(3))) void* las_ptr;

__device__ __forceinline__ void gload_lds16(const void* g, void* l) {
  __builtin_amdgcn_global_load_lds((gas_ptr)(void*)g, (las_ptr)l, 16, 0, 0);
}

// Inputs confirmed fp32 (rounds 2-8 passed with fp32 path).
// T2 swizzle convention for [row][32ch] bf16 tiles (64B rows): 16B-chunk index
// `part` is XORed with (row>>1)&3 on BOTH the producer and consumer side.
// HARD CONSTRAINT (R2/R3 lesson): conv3x3 needs >=2 waves/SIMD (LDS <= 80KB/block);
// 1 block/CU variants lose 2x to exposed ds_read->MFMA latency regardless of schedule.
// MFMA cost model (R4 fix): 16x16x32 is ~19.4 cyc per SIMD (4.85 is the per-CU number).

// ---------------- quaternion block expansion helper ----------------
__device__ __forceinline__ void qexpand(const float* r, const float* i_, const float* j_,
                                        const float* k_, bf16* dst, int O4, int I4, int taps,
                                        int gid) {
  int C = 4 * I4;
  int o   = gid / (taps * C);
  int rem = gid % (taps * C);
  int tap = rem / C, c = rem % C;
  int br = o / O4, orr = o % O4, bc = c / I4, ic = c % I4;
  const float* srcs[4] = { r, i_, j_, k_ };
  const int   comp[4][4] = { {0,1,2,3}, {1,0,3,2}, {2,3,0,1}, {3,2,1,0} };
  const float sgn [4][4] = { {1,-1,-1,-1}, {1,1,-1,1}, {1,1,1,-1}, {1,-1,1,1} };
  float v = srcs[comp[br][bc]][(size_t)(orr * I4 + ic) * taps + tap];
  dst[gid] = __float2bfloat16(v * sgn[br][bc]);
}

// ---------------- one prep kernel: weight expansion + misc cvt + all zero-inits ----------------
#define N_W1 49152
#define N_W2 1327104
#define N_W3 16384
#define N_BR 396288
#define N_MI 900
#define N_SQ 512
#define N_SR 8192
#define N_PREP (N_W1 + N_W2 + N_W3 + N_BR + N_MI + N_SQ + N_SR)

__global__ void prep(const float* __restrict__ qr, const float* __restrict__ qi,
                     const float* __restrict__ qj, const float* __restrict__ qk,
                     const float* __restrict__ dr, const float* __restrict__ di,
                     const float* __restrict__ dj, const float* __restrict__ dk,
                     const float* __restrict__ pr, const float* __restrict__ pi,
                     const float* __restrict__ pj, const float* __restrict__ pk,
                     const float* __restrict__ qb, const float* __restrict__ db,
                     const float* __restrict__ pb, const float* __restrict__ tp,
                     bf16* __restrict__ W1t, bf16* __restrict__ W2t, bf16* __restrict__ W3t,
                     bf16* __restrict__ q1p, float* __restrict__ misc,
                     float* __restrict__ ssq, float* __restrict__ Sraw) {
  int gid = blockIdx.x * 256 + threadIdx.x;
  if (gid < N_W1) { qexpand(qr, qi, qj, qk, W1t, 96, 32, 1, gid); return; }
  gid -= N_W1;
  if (gid < N_W2) { qexpand(dr, di, dj, dk, W2t, 96, 96, 9, gid); return; }
  gid -= N_W2;
  if (gid < N_W3) { qexpand(pr, pi, pj, pk, W3t, 32, 32, 1, gid); return; }
  gid -= N_W3;
  if (gid < N_BR) {
    int b = gid / (516 * 384);
    int rem = gid % (516 * 384);
    int cell = rem / 384, c = rem % 384;
    int hp, wp;
    if      (cell < 130) { hp = 0;   wp = cell; }
    else if (cell < 260) { hp = 129; wp = cell - 130; }
    else if (cell < 388) { hp = cell - 260 + 1; wp = 0; }
    else                 { hp = cell - 388 + 1; wp = 129; }
    q1p[((size_t)((b * 130 + hp) * 130) + wp) * 384 + c] = __float2bfloat16(0.0f);
    return;
  }
  gid -= N_BR;
  if (gid < N_MI) {
    if (gid < 384)      misc[gid] = qb[gid];
    else if (gid < 768) misc[gid] = db[gid - 384];
    else if (gid < 896) misc[gid] = pb[gid - 768];
    else                misc[gid] = tp[gid - 896];
    return;
  }
  gid -= N_MI;
  if (gid < N_SQ) { ssq[gid] = 0.0f; return; }
  gid -= N_SQ;
  if (gid < N_SR) { Sraw[gid] = 0.0f; return; }
}

// ---------------- GEMM1 fused: x NCHW fp32 -> LDS transpose -> 3 o-tiles ----------------
__global__ __launch_bounds__(256) void gemm_qkv1f(const float* __restrict__ x,
                                                  const bf16* __restrict__ wt,
                                                  const float* __restrict__ bias,
                                                  bf16* __restrict__ out) {
  __shared__ __align__(16) bf16 Axl[4 * 64 * 32];   // [kchunk][w64][c32] 16 KB, swizzled
  __shared__ __align__(16) bf16 Bl [4 * 128 * 32];  // [kchunk][o][c32]  32 KB, swizzled
  const int h = blockIdx.x, wh = blockIdx.y, b = blockIdx.z;
  const int tid = threadIdx.x, wid = tid >> 6, lane = tid & 63;
  const int l16 = lane & 15, q = lane >> 4;
  const int sq8 = (q ^ ((l16 >> 1) & 3)) * 8;   // swizzled chunk offset for reads
  const int wm = (wid & 1) * 32, wn = (wid >> 1) * 64;
  {
    const int c = tid >> 1, seg = tid & 1;
    const float* src = x + ((size_t)(b * 128 + c) << 14) + h * 128 + wh * 64 + seg * 32;
    const int cb = (c >> 5) * 2048, c31 = c & 31;
    for (int j = 0; j < 8; ++j) {
      float4 v = *(const float4*)(src + j * 4);
      int w0 = seg * 32 + j * 4;
      float vv[4] = { v.x, v.y, v.z, v.w };
      for (int r = 0; r < 4; ++r) {
        int w = w0 + r;
        Axl[cb + w * 32 + (c31 ^ ((((w >> 1) & 3)) << 3))] = __float2bfloat16(vv[r]);
      }
    }
  }
  for (int ot = 0; ot < 3; ++ot) {
    __syncthreads();
    const bf16* bbase = wt + (size_t)ot * 16384;
    for (int i = 0; i < 8; ++i) {
      int ci = wid * 512 + i * 64 + lane;
      int chunk = ci >> 9, rem = ci & 511;
      int o = rem >> 2, part = rem & 3;
      int ps = part ^ ((o >> 1) & 3);
      gload_lds16(bbase + o * 128 + chunk * 32 + ps * 8, Bl + (size_t)(wid * 512 + i * 64) * 8);
    }
    __syncthreads();
    f32x4 acc[2][4] = {};
    for (int k = 0; k < 4; ++k) {
      bf16x8 af[2], bfr[4];
      for (int mi = 0; mi < 2; ++mi)
        af[mi] = *(const bf16x8*)&Axl[k * 2048 + (wm + mi * 16 + l16) * 32 + sq8];
      for (int ni = 0; ni < 4; ++ni)
        bfr[ni] = *(const bf16x8*)&Bl[k * 4096 + (wn + ni * 16 + l16) * 32 + sq8];
      for (int mi = 0; mi < 2; ++mi)
        for (int ni = 0; ni < 4; ++ni)
          acc[mi][ni] = __builtin_amdgcn_mfma_f32_16x16x32_bf16(af[mi], bfr[ni], acc[mi][ni], 0, 0, 0);
    }
    for (int ni = 0; ni < 4; ++ni) {
      int o = ot * 128 + wn + ni * 16 + l16;
      float bv = bias[o];
      for (int mi = 0; mi < 2; ++mi) {
        int w0 = wh * 64 + wm + mi * 16 + q * 4;
        for (int r = 0; r < 4; ++r) {
          int w = w0 + r;
          size_t idx = ((size_t)((b * 130 + h + 1) * 130) + (w + 1)) * 384 + o;
          out[idx] = __float2bfloat16(acc[mi][ni][r] + bv);
        }
      }
    }
    __syncthreads();
  }
}

// ---------------- conv2 v7 (proven 78 us, 2 blocks/CU) ----------------
__global__ __launch_bounds__(256, 2) void conv3x3(const bf16* __restrict__ in,
                                                  const bf16* __restrict__ wt,
                                                  const float* __restrict__ bias,
                                                  bf16* __restrict__ out) {
  __shared__ __align__(16) short Al[6 * 132 * 32];   // 50688 B, chunk-contiguous, swizzled
  __shared__ __align__(16) short Bl[9 * 48 * 32];    // 27648 B, swizzled
  const int lid = blockIdx.x;
  const int xcd = lid & 7, slot = lid >> 3;
  const int b = xcd & 1;
  const int h0 = (xcd >> 1) * 32 + (slot & 7) * 4;
  const int ob = (slot >> 3) * 48;
  const int tid = threadIdx.x, wid = tid >> 6, lane = tid & 63;
  const int l16 = lane & 15, q = lane >> 4;
  const int sA[3] = { (q ^ (((l16 + 0) >> 1) & 3)) * 8,
                      (q ^ (((l16 + 1) >> 1) & 3)) * 8,
                      (q ^ (((l16 + 2) >> 1) & 3)) * 8 };
  const int sB = sA[0];
  f32x4 acc[8][3] = {};
  const bf16* abase = in + (size_t)b * 130 * 130 * 384;
  const bf16* bbase = wt + (size_t)ob * 3456;
  for (int c0 = 0; c0 < 384; c0 += 32) {
    __syncthreads();
    // A: 3168 chunks (6 rows x 132 w x 4 parts); 792/wave = 12x64 + 24
    for (int i = 0; i < 12; ++i) {
      int g = wid * 792 + i * 64;
      int ci = g + lane;
      int row = ci / 528, rem = ci % 528;
      int w = rem >> 2, part = rem & 3;
      int ps = part ^ ((w >> 1) & 3);
      gload_lds16(abase + ((size_t)(h0 + row) * 130 + w) * 384 + c0 + ps * 8, &Al[g * 8]);
    }
    if (lane < 24) {
      int g = wid * 792 + 768;
      int ci = g + lane;
      int row = ci / 528, rem = ci % 528;
      int w = rem >> 2, part = rem & 3;
      int ps = part ^ ((w >> 1) & 3);
      gload_lds16(abase + ((size_t)(h0 + row) * 130 + w) * 384 + c0 + ps * 8, &Al[g * 8]);
    }
    // B: 1728 chunks (9 taps x 48 o x 4 parts); 432/wave = 6x64 + 48
    for (int i = 0; i < 6; ++i) {
      int g = wid * 432 + i * 64;
      int ci = g + lane;
      int tap = ci / 192, rem = ci % 192;
      int o = rem >> 2, part = rem & 3;
      int ps = part ^ ((o >> 1) & 3);
      gload_lds16(bbase + (size_t)o * 3456 + tap * 384 + c0 + ps * 8, &Bl[g * 8]);
    }
    if (lane < 48) {
      int g = wid * 432 + 384;
      int ci = g + lane;
      int tap = ci / 192, rem = ci % 192;
      int o = rem >> 2, part = rem & 3;
      int ps = part ^ ((o >> 1) & 3);
      gload_lds16(bbase + (size_t)o * 3456 + tap * 384 + c0 + ps * 8, &Bl[g * 8]);
    }
    __syncthreads();
    for (int dh = 0; dh < 3; ++dh)
      for (int dw = 0; dw < 3; ++dw) {
        bf16x8 af[8], bfr[3];
        for (int mi = 0; mi < 8; ++mi)
          af[mi] = *(const bf16x8*)&Al[((wid + dh) * 132 + mi * 16 + l16 + dw) * 32 + sA[dw]];
        for (int ni = 0; ni < 3; ++ni)
          bfr[ni] = *(const bf16x8*)&Bl[((dh * 3 + dw) * 48 + ni * 16 + l16) * 32 + sB];
        for (int mi = 0; mi < 8; ++mi)
          for (int ni = 0; ni < 3; ++ni)
            acc[mi][ni] = __builtin_amdgcn_mfma_f32_16x16x32_bf16(af[mi], bfr[ni], acc[mi][ni], 0, 0, 0);
      }
  }
  const int h = h0 + wid;
  for (int ni = 0; ni < 3; ++ni) {
    int o = ob + ni * 16 + l16;
    float bv = bias[o];
    for (int mi = 0; mi < 8; ++mi) {
      int w0 = mi * 16 + q * 4;
      for (int r = 0; r < 4; ++r) {
        int w = w0 + r;
        out[((size_t)(b * 16384 + h * 128 + w)) * 384 + o] = __float2bfloat16(acc[mi][ni][r] + bv);
      }
    }
  }
}

// ---------------- attn_qk v2: MFMA. S = q.k^T, ssq via qq^T/kk^T diag tiles ----------------
__global__ __launch_bounds__(256) void attn_qk(const bf16* __restrict__ q2,
                                               float* __restrict__ Sraw,
                                               float* __restrict__ ssq) {
  const int sc = blockIdx.x, h = blockIdx.y, b = blockIdx.z;
  const int t = threadIdx.x;
  __shared__ __align__(16) short qkT[64 * 512];   // 64 KB: rows 0..31 = q ch, 32..63 = k ch
  __shared__ float Sl[1024];
  __shared__ float nql[32], nkl[32];
  for (int i = t; i < 1024; i += 256) Sl[i] = 0.0f;
  if (t < 32) nql[t] = 0.0f;
  else if (t < 64) nkl[t - 32] = 0.0f;
  const int ch8 = t & 7, sg = t >> 3;
  const int goff = (ch8 < 4) ? (h * 32 + ch8 * 8) : (128 + h * 32 + (ch8 - 4) * 8);
  const int S0 = sc * 512;
  for (int p = 0; p < 2; ++p) {
    int schunk = sg + p * 32;
    const bf16* src = q2 + (size_t)(b * 16384 + S0 + schunk * 8) * 384 + goff;
    bf16x8 ld[8];
#pragma unroll
    for (int s = 0; s < 8; ++s) ld[s] = *(const bf16x8*)(src + (size_t)s * 384);
#pragma unroll
    for (int j = 0; j < 8; ++j) {
      bf16x8 wv;
#pragma unroll
      for (int s = 0; s < 8; ++s) wv[s] = ld[s][j];
      int row = ch8 * 8 + j;
      int sw = (row ^ (row >> 3)) & 7;
      *(bf16x8*)&qkT[row * 512 + (schunk ^ sw) * 8] = wv;
    }
  }
  __syncthreads();
  const int wid = t >> 6, lane = t & 63;
  const int l16 = lane & 15, q = lane >> 4;
  f32x4 Sacc[2][2] = {};
  f32x4 qqa[2] = {}, kka[2] = {};
  for (int it = 0; it < 4; ++it) {
    int chunkR = wid * 16 + it * 4 + q;
    bf16x8 afq[2], afk[2];
#pragma unroll
    for (int ct = 0; ct < 2; ++ct) {
      int rq = ct * 16 + l16;
      afq[ct] = *(const bf16x8*)&qkT[rq * 512 + (chunkR ^ ((rq ^ (rq >> 3)) & 7)) * 8];
      int rk = 32 + ct * 16 + l16;
      afk[ct] = *(const bf16x8*)&qkT[rk * 512 + (chunkR ^ ((rk ^ (rk >> 3)) & 7)) * 8];
    }
#pragma unroll
    for (int ct = 0; ct < 2; ++ct)
#pragma unroll
      for (int dt = 0; dt < 2; ++dt)
        Sacc[ct][dt] = __builtin_amdgcn_mfma_f32_16x16x32_bf16(afq[ct], afk[dt], Sacc[ct][dt], 0, 0, 0);
#pragma unroll
    for (int ct = 0; ct < 2; ++ct) {
      qqa[ct] = __builtin_amdgcn_mfma_f32_16x16x32_bf16(afq[ct], afq[ct], qqa[ct], 0, 0, 0);
      kka[ct] = __builtin_amdgcn_mfma_f32_16x16x32_bf16(afk[ct], afk[ct], kka[ct], 0, 0, 0);
    }
  }
#pragma unroll
  for (int ct = 0; ct < 2; ++ct)
#pragma unroll
    for (int dt = 0; dt < 2; ++dt)
#pragma unroll
      for (int r = 0; r < 4; ++r)
        atomicAdd(&Sl[(ct * 16 + q * 4 + r) * 32 + dt * 16 + l16], Sacc[ct][dt][r]);
  if ((l16 >> 2) == q) {
    int r = l16 & 3;
#pragma unroll
    for (int ct = 0; ct < 2; ++ct) {
      float vq = r == 0 ? qqa[ct][0] : r == 1 ? qqa[ct][1] : r == 2 ? qqa[ct][2] : qqa[ct][3];
      float vk = r == 0 ? kka[ct][0] : r == 1 ? kka[ct][1] : r == 2 ? kka[ct][2] : kka[ct][3];
      atomicAdd(&nql[ct * 16 + l16], vq);
      atomicAdd(&nkl[ct * 16 + l16], vk);
    }
  }
  __syncthreads();
  float* Sg = Sraw + (size_t)((b * 4 + h) * 1024);
  for (int i = t * 4; i < t * 4 + 4; ++i) atomicAdd(&Sg[i], Sl[i]);
  if (t < 32) atomicAdd(&ssq[b * 256 + h * 32 + t], nql[t]);
  else if (t < 64) atomicAdd(&ssq[b * 256 + 128 + h * 32 + (t - 32)], nkl[t - 32]);
}

// ---------------- attn_out v2: softmax -> Pb (bf16, transposed, swizzled) -> M-build
// via MFMA (wave wid = head hv; A = w3 rows from global, B = Pb rows from LDS) -> GEMM vs v.
// Replaces the scalar M-build (2048 LDS f32 reads + 2048 FMA per thread, ~20 us/grid).
__global__ __launch_bounds__(256) void attn_out(const bf16* __restrict__ q2,
                                                const float* __restrict__ Sraw,
                                                const float* __restrict__ ssq,
                                                const float* __restrict__ misc,
                                                const bf16* __restrict__ w3,
                                                float* __restrict__ out) {
  __shared__ __align__(16) bf16 Ml[4 * 128 * 32];   // 32 KB [hv][o][d32], o-swizzled
  __shared__ __align__(16) bf16 Pb[4 * 32 * 32];    // 8 KB [hv][d][c32], d-swizzled chunks
  __shared__ __align__(16) short Bl[128 * 32];      // 8 KB v-stage, swizzled
  __shared__ float rqa[128], rka[128];
  const int tile = blockIdx.x;
  const int b = tile >> 7, s0 = (tile & 127) * 128;
  const int t = threadIdx.x;
  const int wid = t >> 6, lane = t & 63;
  const int l16 = lane & 15, q = lane >> 4;
  const int sq8 = (q ^ ((l16 >> 1) & 3)) * 8;
  {
    float v = ssq[b * 256 + t];
    float rv = 1.0f / fmaxf(sqrtf(fmaxf(v, 0.0f)), 1e-12f);
    if (t < 128) rqa[t] = rv; else rka[t - 128] = rv;
  }
  __syncthreads();
  if (t < 128) {
    int hh = t >> 5, c = t & 31;
    const float* Sr = Sraw + ((size_t)((b * 4 + hh) * 32 + c)) * 32;
    float tv = misc[896 + hh];
    float rq = rqa[t];
    float row[32];
    float m = -1e30f;
    for (int d = 0; d < 32; ++d) { row[d] = Sr[d] * tv * rq * rka[hh * 32 + d]; m = fmaxf(m, row[d]); }
    float sum = 0.0f;
    for (int d = 0; d < 32; ++d) { row[d] = expf(row[d] - m); sum += row[d]; }
    float inv = 1.0f / sum;
    // transposed store: Pb[hh][d][c], 16B-chunk of c XORed with (d>>1)&3
    for (int d = 0; d < 32; ++d) {
      int cc = (((c >> 3) ^ ((d >> 1) & 3)) << 3) | (c & 7);
      Pb[(hh * 32 + d) * 32 + cc] = __float2bfloat16(row[d] * inv);
    }
  }
  __syncthreads();
  {
    // M-build: wave wid handles head hv=wid. M[o][d] = sum_c w3[o][hv*32+c] * P[hv][c][d].
    // mfma(A=w3 rows o, B=Pb rows d, K=32 c). D: col=l16=d, row=o=ot2*16+q*4+r.
    const int hv = wid;
    bf16x8 bfr[2];
#pragma unroll
    for (int dt = 0; dt < 2; ++dt) {
      int d = dt * 16 + l16;
      bfr[dt] = *(const bf16x8*)&Pb[(hv * 32 + d) * 32 + ((q ^ ((d >> 1) & 3)) << 3)];
    }
    for (int ot2 = 0; ot2 < 8; ++ot2) {
      bf16x8 afw = *(const bf16x8*)&w3[(ot2 * 16 + l16) * 128 + hv * 32 + q * 8];
      f32x4 mb[2] = {};
#pragma unroll
      for (int dt = 0; dt < 2; ++dt)
        mb[dt] = __builtin_amdgcn_mfma_f32_16x16x32_bf16(afw, bfr[dt], mb[dt], 0, 0, 0);
#pragma unroll
      for (int dt = 0; dt < 2; ++dt)
#pragma unroll
        for (int r = 0; r < 4; ++r) {
          int o = ot2 * 16 + q * 4 + r;
          int d = dt * 16 + l16;
          int sw = ((o >> 1) & 3) << 3;
          Ml[hv * 4096 + o * 32 + (d ^ sw)] = __float2bfloat16(mb[dt][r]);
        }
    }
  }
  f32x4 acc[4][4] = {};
  const int wmo = (wid & 1) * 64, wns = (wid >> 1) * 64;
  for (int kc = 0; kc < 4; ++kc) {
    __syncthreads();
    for (int i = 0; i < 2; ++i) {
      int ci = i * 256 + t;
      int s = ci >> 2, part = ci & 3;
      int ps = part ^ ((s >> 1) & 3);
      gload_lds16(q2 + ((size_t)(b * 16384 + s0 + s)) * 384 + 256 + kc * 32 + ps * 8,
                  &Bl[(size_t)(i * 256 + wid * 64) * 8]);
    }
    __syncthreads();
    bf16x8 af[4], bfr[4];
    for (int mi = 0; mi < 4; ++mi)
      af[mi] = *(const bf16x8*)&Ml[kc * 4096 + (wmo + mi * 16 + l16) * 32 + sq8];
    for (int ni = 0; ni < 4; ++ni)
      bfr[ni] = *(const bf16x8*)&Bl[(wns + ni * 16 + l16) * 32 + sq8];
    for (int mi = 0; mi < 4; ++mi)
      for (int ni = 0; ni < 4; ++ni)
        acc[mi][ni] = __builtin_amdgcn_mfma_f32_16x16x32_bf16(af[mi], bfr[ni], acc[mi][ni], 0, 0, 0);
  }
  for (int ni = 0; ni < 4; ++ni) {
    int s = s0 + wns + ni * 16 + l16;
    for (int mi = 0; mi < 4; ++mi) {
      int o0 = wmo + mi * 16 + q * 4;
      for (int r = 0; r < 4; ++r) {
        int o = o0 + r;
        out[(size_t)b * 2097152 + (size_t)o * 16384 + s] = acc[mi][ni][r] + misc[768 + o];
      }
    }
  }
}

extern "C" void kernel_launch(void* const* d_in, const int* in_sizes, int n_in,
                              void* d_out, int out_size, void* d_ws, size_t ws_size,
                              hipStream_t stream) {
  const float* x     = (const float*)d_in[0];
  const float* qkv_r = (const float*)d_in[1];
  const float* qkv_i = (const float*)d_in[2];
  const float* qkv_j = (const float*)d_in[3];
  const float* qkv_k = (const float*)d_in[4];
  const float* qkv_b = (const float*)d_in[5];
  const float* dw_r  = (const float*)d_in[6];
  const float* dw_i  = (const float*)d_in[7];
  const float* dw_j  = (const float*)d_in[8];
  const float* dw_k  = (const float*)d_in[9];
  const float* dw_b  = (const float*)d_in[10];
  const float* po_r  = (const float*)d_in[11];
  const float* po_i  = (const float*)d_in[12];
  const float* po_j  = (const float*)d_in[13];
  const float* po_k  = (const float*)d_in[14];
  const float* po_b  = (const float*)d_in[15];
  const float* temp  = (const float*)d_in[16];

  char* ws = (char*)d_ws;
  size_t off = 0;
  auto alloc = [&](size_t bytes) { char* p = ws + off; off += (bytes + 255) & ~(size_t)255; return p; };
  bf16* q1p  = (bf16*)alloc((size_t)2 * 130 * 130 * 384 * 2);
  bf16* q2   = (bf16*)alloc((size_t)2 * 16384 * 384 * 2);
  bf16* W1t  = (bf16*)alloc((size_t)384 * 128 * 2);
  bf16* W2t  = (bf16*)alloc((size_t)384 * 3456 * 2);
  bf16* W3t  = (bf16*)alloc((size_t)128 * 128 * 2);
  float* ssq  = (float*)alloc((size_t)2 * 256 * 4);
  float* Sraw = (float*)alloc((size_t)2 * 4 * 32 * 32 * 4);
  float* misc = (float*)alloc((size_t)900 * 4);

  prep<<<(N_PREP + 255) / 256, 256, 0, stream>>>(qkv_r, qkv_i, qkv_j, qkv_k,
                                                 dw_r, dw_i, dw_j, dw_k,
                                                 po_r, po_i, po_j, po_k,
                                                 qkv_b, dw_b, po_b, temp,
                                                 W1t, W2t, W3t, q1p, misc, ssq, Sraw);
  gemm_qkv1f<<<dim3(128, 2, 2), 256, 0, stream>>>(x, W1t, misc, q1p);
  conv3x3<<<512, 256, 0, stream>>>(q1p, W2t, misc + 384, q2);
  attn_qk<<<dim3(32, 4, 2), 256, 0, stream>>>(q2, Sraw, ssq);
  attn_out<<<256, 256, 0, stream>>>(q2, Sraw, ssq, misc, W3t, (float*)d_out);
}

// Round 6
// 201.775 us; speedup vs baseline: 1.2649x; 1.0079x over previous
//
#include <hip/hip_runtime.h>
#include <hip/hip_bf16.h>
#include <string.h>

typedef __hip_bfloat16 bf16;
typedef __bf16 bf16x8 __attribute__((ext_vector_type(8)));
typedef float f32x4 __attribute__((ext_vector_type(4)));

typedef __attribute__((address_space(1))) void* gas_ptr;
typedef __attribute__((address_space(3))) void* las_ptr;

__device__ __forceinline__ void gload_lds16(const void* g, void* l) {
  __builtin_amdgcn_global_load_lds((gas_ptr)(void*)g, (las_ptr)l, 16, 0, 0);
}

// Inputs confirmed fp32 (rounds 2-8 passed with fp32 path).
// T2 swizzle convention for [row][32ch] bf16 tiles (64B rows): 16B-chunk index
// `part` is XORed with (row>>1)&3 on BOTH the producer and consumer side.
// HARD CONSTRAINT (R2/R3 lesson): conv3x3 needs >=2 waves/SIMD (LDS <= 80KB/block);
// 1 block/CU variants lose 2x to exposed ds_read->MFMA latency regardless of schedule.
// MFMA cost model (R4 fix): 16x16x32 is ~19.4 cyc per SIMD (4.85 is the per-CU number).

// ---------------- quaternion block expansion, 8-wide vectorized ----------------
// 8 consecutive gid share (o, tap, bc) because I4 is a multiple of 8 -> one 16B store.
__device__ __forceinline__ void qexpand8(const float* r, const float* i_, const float* j_,
                                         const float* k_, bf16* dst, int O4, int I4, int taps,
                                         int vid) {
  int C = 4 * I4;
  int gid0 = vid * 8;
  int o   = gid0 / (taps * C);
  int rem = gid0 % (taps * C);
  int tap = rem / C, c0 = rem % C;
  int br = o / O4, orr = o % O4, bc = c0 / I4, ic0 = c0 % I4;
  const float* srcs[4] = { r, i_, j_, k_ };
  const int   comp[4][4] = { {0,1,2,3}, {1,0,3,2}, {2,3,0,1}, {3,2,1,0} };
  const float sgn [4][4] = { {1,-1,-1,-1}, {1,1,-1,1}, {1,1,1,-1}, {1,-1,1,1} };
  const float* s = srcs[comp[br][bc]];
  float sg = sgn[br][bc];
  size_t base = (size_t)(orr * I4 + ic0) * taps + tap;
  bf16x8 v;
#pragma unroll
  for (int j = 0; j < 8; ++j) {
    __hip_bfloat16 h = __float2bfloat16(s[base + (size_t)j * taps] * sg);
    v[j] = *reinterpret_cast<__bf16*>(&h);
  }
  *(bf16x8*)(dst + gid0) = v;
}

// ---------------- one prep kernel (x8-vectorized): weight expansion + misc + zero-inits ----------------
#define N_W1V 6144
#define N_W2V 165888
#define N_W3V 2048
#define N_BRV 49536
#define N_MI 900
#define N_SQ 512
#define N_SR 8192
#define N_PREPV (N_W1V + N_W2V + N_W3V + N_BRV + N_MI + N_SQ + N_SR)

__global__ void prep(const float* __restrict__ qr, const float* __restrict__ qi,
                     const float* __restrict__ qj, const float* __restrict__ qk,
                     const float* __restrict__ dr, const float* __restrict__ di,
                     const float* __restrict__ dj, const float* __restrict__ dk,
                     const float* __restrict__ pr, const float* __restrict__ pi,
                     const float* __restrict__ pj, const float* __restrict__ pk,
                     const float* __restrict__ qb, const float* __restrict__ db,
                     const float* __restrict__ pb, const float* __restrict__ tp,
                     bf16* __restrict__ W1t, bf16* __restrict__ W2t, bf16* __restrict__ W3t,
                     bf16* __restrict__ q1p, float* __restrict__ misc,
                     float* __restrict__ ssq, float* __restrict__ Sraw) {
  int gid = blockIdx.x * 256 + threadIdx.x;
  if (gid < N_W1V) { qexpand8(qr, qi, qj, qk, W1t, 96, 32, 1, gid); return; }
  gid -= N_W1V;
  if (gid < N_W2V) { qexpand8(dr, di, dj, dk, W2t, 96, 96, 9, gid); return; }
  gid -= N_W2V;
  if (gid < N_W3V) { qexpand8(pr, pi, pj, pk, W3t, 32, 32, 1, gid); return; }
  gid -= N_W3V;
  if (gid < N_BRV) {
    int b = gid / (516 * 48);
    int rem = gid % (516 * 48);
    int cell = rem / 48, cc = (rem % 48) * 8;
    int hp, wp;
    if      (cell < 130) { hp = 0;   wp = cell; }
    else if (cell < 260) { hp = 129; wp = cell - 130; }
    else if (cell < 388) { hp = cell - 260 + 1; wp = 0; }
    else                 { hp = cell - 388 + 1; wp = 129; }
    float4 z = make_float4(0.f, 0.f, 0.f, 0.f);
    *(float4*)&q1p[((size_t)((b * 130 + hp) * 130) + wp) * 384 + cc] = z;
    return;
  }
  gid -= N_BRV;
  if (gid < N_MI) {
    if (gid < 384)      misc[gid] = qb[gid];
    else if (gid < 768) misc[gid] = db[gid - 384];
    else if (gid < 896) misc[gid] = pb[gid - 768];
    else                misc[gid] = tp[gid - 896];
    return;
  }
  gid -= N_MI;
  if (gid < N_SQ) { ssq[gid] = 0.0f; return; }
  gid -= N_SQ;
  if (gid < N_SR) { Sraw[gid] = 0.0f; return; }
}

// ---------------- GEMM1 fused: x NCHW fp32 -> LDS transpose -> 3 o-tiles ----------------
// Epilogue v2: C bounced through LDS (aliases Bl, dead post-MFMA) -> full-line 16B stores.
__global__ __launch_bounds__(256) void gemm_qkv1f(const float* __restrict__ x,
                                                  const bf16* __restrict__ wt,
                                                  const float* __restrict__ bias,
                                                  bf16* __restrict__ out) {
  __shared__ __align__(16) bf16 Axl[4 * 64 * 32];   // [kchunk][w64][c32] 16 KB, swizzled
  __shared__ __align__(16) bf16 Bl [4 * 128 * 32];  // [kchunk][o][c32]  32 KB, swizzled; aliased as Cl
  const int h = blockIdx.x, wh = blockIdx.y, b = blockIdx.z;
  const int tid = threadIdx.x, wid = tid >> 6, lane = tid & 63;
  const int l16 = lane & 15, q = lane >> 4;
  const int sq8 = (q ^ ((l16 >> 1) & 3)) * 8;   // swizzled chunk offset for reads
  const int wm = (wid & 1) * 32, wn = (wid >> 1) * 64;
  {
    const int c = tid >> 1, seg = tid & 1;
    const float* src = x + ((size_t)(b * 128 + c) << 14) + h * 128 + wh * 64 + seg * 32;
    const int cb = (c >> 5) * 2048, c31 = c & 31;
    for (int j = 0; j < 8; ++j) {
      float4 v = *(const float4*)(src + j * 4);
      int w0 = seg * 32 + j * 4;
      float vv[4] = { v.x, v.y, v.z, v.w };
      for (int r = 0; r < 4; ++r) {
        int w = w0 + r;
        Axl[cb + w * 32 + (c31 ^ ((((w >> 1) & 3)) << 3))] = __float2bfloat16(vv[r]);
      }
    }
  }
  for (int ot = 0; ot < 3; ++ot) {
    __syncthreads();
    const bf16* bbase = wt + (size_t)ot * 16384;
    for (int i = 0; i < 8; ++i) {
      int ci = wid * 512 + i * 64 + lane;
      int chunk = ci >> 9, rem = ci & 511;
      int o = rem >> 2, part = rem & 3;
      int ps = part ^ ((o >> 1) & 3);
      gload_lds16(bbase + o * 128 + chunk * 32 + ps * 8, Bl + (size_t)(wid * 512 + i * 64) * 8);
    }
    __syncthreads();
    f32x4 acc[2][4] = {};
    for (int k = 0; k < 4; ++k) {
      bf16x8 af[2], bfr[4];
      for (int mi = 0; mi < 2; ++mi)
        af[mi] = *(const bf16x8*)&Axl[k * 2048 + (wm + mi * 16 + l16) * 32 + sq8];
      for (int ni = 0; ni < 4; ++ni)
        bfr[ni] = *(const bf16x8*)&Bl[k * 4096 + (wn + ni * 16 + l16) * 32 + sq8];
      for (int mi = 0; mi < 2; ++mi)
        for (int ni = 0; ni < 4; ++ni)
          acc[mi][ni] = __builtin_amdgcn_mfma_f32_16x16x32_bf16(af[mi], bfr[ni], acc[mi][ni], 0, 0, 0);
    }
    __syncthreads();
    {
      short* Cl = (short*)Bl;  // [64 w][128 o], o-chunk swizzled by (w>>2)&3
      for (int ni = 0; ni < 4; ++ni) {
        int o = wn + ni * 16 + l16;
        float bv = bias[ot * 128 + o];
        for (int mi = 0; mi < 2; ++mi) {
          for (int r = 0; r < 4; ++r) {
            int w = wm + mi * 16 + q * 4 + r;
            int sw = ((w >> 2) & 3) << 3;
            __hip_bfloat16 hv = __float2bfloat16(acc[mi][ni][r] + bv);
            Cl[w * 128 + (o ^ sw)] = *reinterpret_cast<short*>(&hv);
          }
        }
      }
    }
    __syncthreads();
    {
      const short* Cl = (const short*)Bl;
      const size_t rowb = (size_t)(b * 130 + h + 1) * 130;
      for (int i = 0; i < 4; ++i) {
        int cid = i * 256 + tid;
        int w = cid >> 4, part = cid & 15;
        int sw = ((w >> 2) & 3) << 3;
        bf16x8 v = *(const bf16x8*)&Cl[w * 128 + ((part * 8) ^ sw)];
        *(bf16x8*)&out[(rowb + (wh * 64 + w + 1)) * 384 + ot * 128 + part * 8] = v;
      }
    }
  }
}

// ---------------- conv2 v7 (proven 78 us, 2 blocks/CU) ----------------
__global__ __launch_bounds__(256, 2) void conv3x3(const bf16* __restrict__ in,
                                                  const bf16* __restrict__ wt,
                                                  const float* __restrict__ bias,
                                                  bf16* __restrict__ out) {
  __shared__ __align__(16) short Al[6 * 132 * 32];   // 50688 B, chunk-contiguous, swizzled
  __shared__ __align__(16) short Bl[9 * 48 * 32];    // 27648 B, swizzled
  const int lid = blockIdx.x;
  const int xcd = lid & 7, slot = lid >> 3;
  const int b = xcd & 1;
  const int h0 = (xcd >> 1) * 32 + (slot & 7) * 4;
  const int ob = (slot >> 3) * 48;
  const int tid = threadIdx.x, wid = tid >> 6, lane = tid & 63;
  const int l16 = lane & 15, q = lane >> 4;
  const int sA[3] = { (q ^ (((l16 + 0) >> 1) & 3)) * 8,
                      (q ^ (((l16 + 1) >> 1) & 3)) * 8,
                      (q ^ (((l16 + 2) >> 1) & 3)) * 8 };
  const int sB = sA[0];
  f32x4 acc[8][3] = {};
  const bf16* abase = in + (size_t)b * 130 * 130 * 384;
  const bf16* bbase = wt + (size_t)ob * 3456;
  for (int c0 = 0; c0 < 384; c0 += 32) {
    __syncthreads();
    // A: 3168 chunks (6 rows x 132 w x 4 parts); 792/wave = 12x64 + 24
    for (int i = 0; i < 12; ++i) {
      int g = wid * 792 + i * 64;
      int ci = g + lane;
      int row = ci / 528, rem = ci % 528;
      int w = rem >> 2, part = rem & 3;
      int ps = part ^ ((w >> 1) & 3);
      gload_lds16(abase + ((size_t)(h0 + row) * 130 + w) * 384 + c0 + ps * 8, &Al[g * 8]);
    }
    if (lane < 24) {
      int g = wid * 792 + 768;
      int ci = g + lane;
      int row = ci / 528, rem = ci % 528;
      int w = rem >> 2, part = rem & 3;
      int ps = part ^ ((w >> 1) & 3);
      gload_lds16(abase + ((size_t)(h0 + row) * 130 + w) * 384 + c0 + ps * 8, &Al[g * 8]);
    }
    // B: 1728 chunks (9 taps x 48 o x 4 parts); 432/wave = 6x64 + 48
    for (int i = 0; i < 6; ++i) {
      int g = wid * 432 + i * 64;
      int ci = g + lane;
      int tap = ci / 192, rem = ci % 192;
      int o = rem >> 2, part = rem & 3;
      int ps = part ^ ((o >> 1) & 3);
      gload_lds16(bbase + (size_t)o * 3456 + tap * 384 + c0 + ps * 8, &Bl[g * 8]);
    }
    if (lane < 48) {
      int g = wid * 432 + 384;
      int ci = g + lane;
      int tap = ci / 192, rem = ci % 192;
      int o = rem >> 2, part = rem & 3;
      int ps = part ^ ((o >> 1) & 3);
      gload_lds16(bbase + (size_t)o * 3456 + tap * 384 + c0 + ps * 8, &Bl[g * 8]);
    }
    __syncthreads();
    for (int dh = 0; dh < 3; ++dh)
      for (int dw = 0; dw < 3; ++dw) {
        bf16x8 af[8], bfr[3];
        for (int mi = 0; mi < 8; ++mi)
          af[mi] = *(const bf16x8*)&Al[((wid + dh) * 132 + mi * 16 + l16 + dw) * 32 + sA[dw]];
        for (int ni = 0; ni < 3; ++ni)
          bfr[ni] = *(const bf16x8*)&Bl[((dh * 3 + dw) * 48 + ni * 16 + l16) * 32 + sB];
        for (int mi = 0; mi < 8; ++mi)
          for (int ni = 0; ni < 3; ++ni)
            acc[mi][ni] = __builtin_amdgcn_mfma_f32_16x16x32_bf16(af[mi], bfr[ni], acc[mi][ni], 0, 0, 0);
      }
  }
  const int h = h0 + wid;
  for (int ni = 0; ni < 3; ++ni) {
    int o = ob + ni * 16 + l16;
    float bv = bias[o];
    for (int mi = 0; mi < 8; ++mi) {
      int w0 = mi * 16 + q * 4;
      for (int r = 0; r < 4; ++r) {
        int w = w0 + r;
        out[((size_t)(b * 16384 + h * 128 + w)) * 384 + o] = __float2bfloat16(acc[mi][ni][r] + bv);
      }
    }
  }
}

// ---------------- attn_qk v2: MFMA. S = q.k^T, ssq via qq^T/kk^T diag tiles ----------------
__global__ __launch_bounds__(256) void attn_qk(const bf16* __restrict__ q2,
                                               float* __restrict__ Sraw,
                                               float* __restrict__ ssq) {
  const int sc = blockIdx.x, h = blockIdx.y, b = blockIdx.z;
  const int t = threadIdx.x;
  __shared__ __align__(16) short qkT[64 * 512];   // 64 KB: rows 0..31 = q ch, 32..63 = k ch
  __shared__ float Sl[1024];
  __shared__ float nql[32], nkl[32];
  for (int i = t; i < 1024; i += 256) Sl[i] = 0.0f;
  if (t < 32) nql[t] = 0.0f;
  else if (t < 64) nkl[t - 32] = 0.0f;
  const int ch8 = t & 7, sg = t >> 3;
  const int goff = (ch8 < 4) ? (h * 32 + ch8 * 8) : (128 + h * 32 + (ch8 - 4) * 8);
  const int S0 = sc * 512;
  for (int p = 0; p < 2; ++p) {
    int schunk = sg + p * 32;
    const bf16* src = q2 + (size_t)(b * 16384 + S0 + schunk * 8) * 384 + goff;
    bf16x8 ld[8];
#pragma unroll
    for (int s = 0; s < 8; ++s) ld[s] = *(const bf16x8*)(src + (size_t)s * 384);
#pragma unroll
    for (int j = 0; j < 8; ++j) {
      bf16x8 wv;
#pragma unroll
      for (int s = 0; s < 8; ++s) wv[s] = ld[s][j];
      int row = ch8 * 8 + j;
      int sw = (row ^ (row >> 3)) & 7;
      *(bf16x8*)&qkT[row * 512 + (schunk ^ sw) * 8] = wv;
    }
  }
  __syncthreads();
  const int wid = t >> 6, lane = t & 63;
  const int l16 = lane & 15, q = lane >> 4;
  f32x4 Sacc[2][2] = {};
  f32x4 qqa[2] = {}, kka[2] = {};
  for (int it = 0; it < 4; ++it) {
    int chunkR = wid * 16 + it * 4 + q;
    bf16x8 afq[2], afk[2];
#pragma unroll
    for (int ct = 0; ct < 2; ++ct) {
      int rq = ct * 16 + l16;
      afq[ct] = *(const bf16x8*)&qkT[rq * 512 + (chunkR ^ ((rq ^ (rq >> 3)) & 7)) * 8];
      int rk = 32 + ct * 16 + l16;
      afk[ct] = *(const bf16x8*)&qkT[rk * 512 + (chunkR ^ ((rk ^ (rk >> 3)) & 7)) * 8];
    }
#pragma unroll
    for (int ct = 0; ct < 2; ++ct)
#pragma unroll
      for (int dt = 0; dt < 2; ++dt)
        Sacc[ct][dt] = __builtin_amdgcn_mfma_f32_16x16x32_bf16(afq[ct], afk[dt], Sacc[ct][dt], 0, 0, 0);
#pragma unroll
    for (int ct = 0; ct < 2; ++ct) {
      qqa[ct] = __builtin_amdgcn_mfma_f32_16x16x32_bf16(afq[ct], afq[ct], qqa[ct], 0, 0, 0);
      kka[ct] = __builtin_amdgcn_mfma_f32_16x16x32_bf16(afk[ct], afk[ct], kka[ct], 0, 0, 0);
    }
  }
#pragma unroll
  for (int ct = 0; ct < 2; ++ct)
#pragma unroll
    for (int dt = 0; dt < 2; ++dt)
#pragma unroll
      for (int r = 0; r < 4; ++r)
        atomicAdd(&Sl[(ct * 16 + q * 4 + r) * 32 + dt * 16 + l16], Sacc[ct][dt][r]);
  if ((l16 >> 2) == q) {
    int r = l16 & 3;
#pragma unroll
    for (int ct = 0; ct < 2; ++ct) {
      float vq = r == 0 ? qqa[ct][0] : r == 1 ? qqa[ct][1] : r == 2 ? qqa[ct][2] : qqa[ct][3];
      float vk = r == 0 ? kka[ct][0] : r == 1 ? kka[ct][1] : r == 2 ? kka[ct][2] : kka[ct][3];
      atomicAdd(&nql[ct * 16 + l16], vq);
      atomicAdd(&nkl[ct * 16 + l16], vk);
    }
  }
  __syncthreads();
  float* Sg = Sraw + (size_t)((b * 4 + h) * 1024);
  for (int i = t * 4; i < t * 4 + 4; ++i) atomicAdd(&Sg[i], Sl[i]);
  if (t < 32) atomicAdd(&ssq[b * 256 + h * 32 + t], nql[t]);
  else if (t < 64) atomicAdd(&ssq[b * 256 + 128 + h * 32 + (t - 32)], nkl[t - 32]);
}

// ---------------- attn_out v2: softmax -> Pb (bf16, transposed, swizzled) -> M-build
// via MFMA (wave wid = head hv; A = w3 rows from global, B = Pb rows from LDS) -> GEMM vs v.
__global__ __launch_bounds__(256) void attn_out(const bf16* __restrict__ q2,
                                                const float* __restrict__ Sraw,
                                                const float* __restrict__ ssq,
                                                const float* __restrict__ misc,
                                                const bf16* __restrict__ w3,
                                                float* __restrict__ out) {
  __shared__ __align__(16) bf16 Ml[4 * 128 * 32];   // 32 KB [hv][o][d32], o-swizzled
  __shared__ __align__(16) bf16 Pb[4 * 32 * 32];    // 8 KB [hv][d][c32], d-swizzled chunks
  __shared__ __align__(16) short Bl[128 * 32];      // 8 KB v-stage, swizzled
  __shared__ float rqa[128], rka[128];
  const int tile = blockIdx.x;
  const int b = tile >> 7, s0 = (tile & 127) * 128;
  const int t = threadIdx.x;
  const int wid = t >> 6, lane = t & 63;
  const int l16 = lane & 15, q = lane >> 4;
  const int sq8 = (q ^ ((l16 >> 1) & 3)) * 8;
  {
    float v = ssq[b * 256 + t];
    float rv = 1.0f / fmaxf(sqrtf(fmaxf(v, 0.0f)), 1e-12f);
    if (t < 128) rqa[t] = rv; else rka[t - 128] = rv;
  }
  __syncthreads();
  if (t < 128) {
    int hh = t >> 5, c = t & 31;
    const float* Sr = Sraw + ((size_t)((b * 4 + hh) * 32 + c)) * 32;
    float tv = misc[896 + hh];
    float rq = rqa[t];
    float row[32];
    float m = -1e30f;
    for (int d = 0; d < 32; ++d) { row[d] = Sr[d] * tv * rq * rka[hh * 32 + d]; m = fmaxf(m, row[d]); }
    float sum = 0.0f;
    for (int d = 0; d < 32; ++d) { row[d] = expf(row[d] - m); sum += row[d]; }
    float inv = 1.0f / sum;
    // transposed store: Pb[hh][d][c], 16B-chunk of c XORed with (d>>1)&3
    for (int d = 0; d < 32; ++d) {
      int cc = (((c >> 3) ^ ((d >> 1) & 3)) << 3) | (c & 7);
      Pb[(hh * 32 + d) * 32 + cc] = __float2bfloat16(row[d] * inv);
    }
  }
  __syncthreads();
  {
    // M-build: wave wid handles head hv=wid. M[o][d] = sum_c w3[o][hv*32+c] * P[hv][c][d].
    const int hv = wid;
    bf16x8 bfr[2];
#pragma unroll
    for (int dt = 0; dt < 2; ++dt) {
      int d = dt * 16 + l16;
      bfr[dt] = *(const bf16x8*)&Pb[(hv * 32 + d) * 32 + ((q ^ ((d >> 1) & 3)) << 3)];
    }
    for (int ot2 = 0; ot2 < 8; ++ot2) {
      bf16x8 afw = *(const bf16x8*)&w3[(ot2 * 16 + l16) * 128 + hv * 32 + q * 8];
      f32x4 mb[2] = {};
#pragma unroll
      for (int dt = 0; dt < 2; ++dt)
        mb[dt] = __builtin_amdgcn_mfma_f32_16x16x32_bf16(afw, bfr[dt], mb[dt], 0, 0, 0);
#pragma unroll
      for (int dt = 0; dt < 2; ++dt)
#pragma unroll
        for (int r = 0; r < 4; ++r) {
          int o = ot2 * 16 + q * 4 + r;
          int d = dt * 16 + l16;
          int sw = ((o >> 1) & 3) << 3;
          Ml[hv * 4096 + o * 32 + (d ^ sw)] = __float2bfloat16(mb[dt][r]);
        }
    }
  }
  f32x4 acc[4][4] = {};
  const int wmo = (wid & 1) * 64, wns = (wid >> 1) * 64;
  for (int kc = 0; kc < 4; ++kc) {
    __syncthreads();
    for (int i = 0; i < 2; ++i) {
      int ci = i * 256 + t;
      int s = ci >> 2, part = ci & 3;
      int ps = part ^ ((s >> 1) & 3);
      gload_lds16(q2 + ((size_t)(b * 16384 + s0 + s)) * 384 + 256 + kc * 32 + ps * 8,
                  &Bl[(size_t)(i * 256 + wid * 64) * 8]);
    }
    __syncthreads();
    bf16x8 af[4], bfr[4];
    for (int mi = 0; mi < 4; ++mi)
      af[mi] = *(const bf16x8*)&Ml[kc * 4096 + (wmo + mi * 16 + l16) * 32 + sq8];
    for (int ni = 0; ni < 4; ++ni)
      bfr[ni] = *(const bf16x8*)&Bl[(wns + ni * 16 + l16) * 32 + sq8];
    for (int mi = 0; mi < 4; ++mi)
      for (int ni = 0; ni < 4; ++ni)
        acc[mi][ni] = __builtin_amdgcn_mfma_f32_16x16x32_bf16(af[mi], bfr[ni], acc[mi][ni], 0, 0, 0);
  }
  for (int ni = 0; ni < 4; ++ni) {
    int s = s0 + wns + ni * 16 + l16;
    for (int mi = 0; mi < 4; ++mi) {
      int o0 = wmo + mi * 16 + q * 4;
      for (int r = 0; r < 4; ++r) {
        int o = o0 + r;
        out[(size_t)b * 2097152 + (size_t)o * 16384 + s] = acc[mi][ni][r] + misc[768 + o];
      }
    }
  }
}

extern "C" void kernel_launch(void* const* d_in, const int* in_sizes, int n_in,
                              void* d_out, int out_size, void* d_ws, size_t ws_size,
                              hipStream_t stream) {
  const float* x     = (const float*)d_in[0];
  const float* qkv_r = (const float*)d_in[1];
  const float* qkv_i = (const float*)d_in[2];
  const float* qkv_j = (const float*)d_in[3];
  const float* qkv_k = (const float*)d_in[4];
  const float* qkv_b = (const float*)d_in[5];
  const float* dw_r  = (const float*)d_in[6];
  const float* dw_i  = (const float*)d_in[7];
  const float* dw_j  = (const float*)d_in[8];
  const float* dw_k  = (const float*)d_in[9];
  const float* dw_b  = (const float*)d_in[10];
  const float* po_r  = (const float*)d_in[11];
  const float* po_i  = (const float*)d_in[12];
  const float* po_j  = (const float*)d_in[13];
  const float* po_k  = (const float*)d_in[14];
  const float* po_b  = (const float*)d_in[15];
  const float* temp  = (const float*)d_in[16];

  char* ws = (char*)d_ws;
  size_t off = 0;
  auto alloc = [&](size_t bytes) { char* p = ws + off; off += (bytes + 255) & ~(size_t)255; return p; };
  bf16* q1p  = (bf16*)alloc((size_t)2 * 130 * 130 * 384 * 2);
  bf16* q2   = (bf16*)alloc((size_t)2 * 16384 * 384 * 2);
  bf16* W1t  = (bf16*)alloc((size_t)384 * 128 * 2);
  bf16* W2t  = (bf16*)alloc((size_t)384 * 3456 * 2);
  bf16* W3t  = (bf16*)alloc((size_t)128 * 128 * 2);
  float* ssq  = (float*)alloc((size_t)2 * 256 * 4);
  float* Sraw = (float*)alloc((size_t)2 * 4 * 32 * 32 * 4);
  float* misc = (float*)alloc((size_t)900 * 4);

  prep<<<(N_PREPV + 255) / 256, 256, 0, stream>>>(qkv_r, qkv_i, qkv_j, qkv_k,
                                                  dw_r, dw_i, dw_j, dw_k,
                                                  po_r, po_i, po_j, po_k,
                                                  qkv_b, dw_b, po_b, temp,
                                                  W1t, W2t, W3t, q1p, misc, ssq, Sraw);
  gemm_qkv1f<<<dim3(128, 2, 2), 256, 0, stream>>>(x, W1t, misc, q1p);
  conv3x3<<<512, 256, 0, stream>>>(q1p, W2t, misc + 384, q2);
  attn_qk<<<dim3(32, 4, 2), 256, 0, stream>>>(q2, Sraw, ssq);
  attn_out<<<256, 256, 0, stream>>>(q2, Sraw, ssq, misc, W3t, (float*)d_out);
}